// Round 3
// baseline (4167.636 us; speedup 1.0000x reference)
//
#include <hip/hip_runtime.h>
#include <cstdint>
#include <cstddef>

#define NB 4
#define NN 8192
#define NPTS 2048
#define NSAMP 32
#define NC 128
#define CIN 131      // 3 + NC
#define NH1 64
#define NH2 128
#define NOUTC 128
#define GCELLS 4096  // 16x16x16 morton grid

typedef float v2f __attribute__((ext_vector_type(2)));

// Exact (numpy-order, contraction-free) squared distance:
// ((dx*dx + dy*dy) + dz*dz), round-to-nearest each op, no FMA.
__device__ __forceinline__ float d2_exact(float ax, float ay, float az,
                                          float bx, float by, float bz) {
  float dx = ax - bx, dy = ay - by, dz = az - bz;
  return __fadd_rn(__fadd_rn(__fmul_rn(dx, dx), __fmul_rn(dy, dy)),
                   __fmul_rn(dz, dz));
}

// ---- DPP cross-lane (VALU, no LDS) --------------------------------------
#if __has_builtin(__builtin_amdgcn_mov_dpp)
template <int CTRL>
__device__ __forceinline__ float dppf(float v) {
  return __int_as_float(
      __builtin_amdgcn_mov_dpp(__float_as_int(v), CTRL, 0xF, 0xF, true));
}
template <int CTRL>
__device__ __forceinline__ int dppi(int v) {
  return __builtin_amdgcn_mov_dpp(v, CTRL, 0xF, 0xF, true);
}
#else
template <int CTRL>
__device__ __forceinline__ float dppf(float v) {
  const int m = (CTRL == 0xB1) ? 1 : (CTRL == 0x4E) ? 2 : (CTRL == 0x141) ? 7 : 15;
  return __shfl_xor(v, m);
}
template <int CTRL>
__device__ __forceinline__ int dppi(int v) {
  const int m = (CTRL == 0xB1) ? 1 : (CTRL == 0x4E) ? 2 : (CTRL == 0x141) ? 7 : 15;
  return __shfl_xor(v, m);
}
#endif

// argmax combine: larger value wins; on equal value, smaller index wins
__device__ __forceinline__ void red_pair(float& bv, int& bi, float ov, int oi) {
  bool t = (ov > bv) || (ov == bv && oi < bi);
  bv = t ? ov : bv;
  bi = t ? oi : bi;
}
__device__ __forceinline__ void red3(float& bv, int& bi, int& bs,
                                     float ov, int oi, int os) {
  bool t = (ov > bv) || (ov == bv && oi < bi);
  bv = t ? ov : bv;
  bi = t ? oi : bi;
  bs = t ? os : bs;
}

// ---------------------------------------------------------------------------
// Spatial counting sort into 16^3 morton cells (one block per batch).
// Order within a cell is nondeterministic (LDS atomics) — harmless: FPS
// selection is order-independent (total order on (value, orig_idx)).
// ---------------------------------------------------------------------------
__device__ __forceinline__ int spread3(int v) {  // 4 bits -> every 3rd bit
  return (v & 1) | ((v & 2) << 2) | ((v & 4) << 4) | ((v & 8) << 6);
}

__global__ __launch_bounds__(1024, 1) void sort_kernel(
    const float* __restrict__ xyz, float* __restrict__ xs,
    float* __restrict__ ys, float* __restrict__ zs, int* __restrict__ io) {
  __shared__ int hist[GCELLS];
  __shared__ int cbase[GCELLS];
  __shared__ int wtot[16];
  __shared__ int woff[16];
  const int b = blockIdx.x;
  const int tid = threadIdx.x;
  const int lane = tid & 63;
  const int wid = tid >> 6;
  const float* xb = xyz + (size_t)b * NN * 3;
  for (int i = tid; i < GCELLS; i += 1024) hist[i] = 0;
  __syncthreads();
  int cell[8];
  float px[8], py[8], pz[8];
#pragma unroll
  for (int k = 0; k < 8; ++k) {
    int j = tid + (k << 10);
    float x = xb[j * 3 + 0], y = xb[j * 3 + 1], z = xb[j * 3 + 2];
    px[k] = x; py[k] = y; pz[k] = z;
    int cx = min(15, max(0, (int)(x * 16.0f)));
    int cy = min(15, max(0, (int)(y * 16.0f)));
    int cz = min(15, max(0, (int)(z * 16.0f)));
    cell[k] = spread3(cx) | (spread3(cy) << 1) | (spread3(cz) << 2);
    atomicAdd(&hist[cell[k]], 1);
  }
  __syncthreads();
  // prefix sum over 4096 cells: 4 cells/thread -> wave scan -> wave offsets
  const int i0 = tid * 4;
  int h0 = hist[i0], h1 = hist[i0 + 1], h2 = hist[i0 + 2], h3 = hist[i0 + 3];
  int s4 = h0 + h1 + h2 + h3;
  int v = s4;
#pragma unroll
  for (int d = 1; d < 64; d <<= 1) {
    int o = __shfl_up(v, d);
    if (lane >= d) v += o;
  }
  if (lane == 63) wtot[wid] = v;
  __syncthreads();
  if (tid < 16) {
    int acc = 0;
    for (int w = 0; w < 16; ++w) {  // tiny serial scan, 16 iters
      if (w == tid) woff[tid] = acc;
      acc += wtot[w];
    }
  }
  __syncthreads();
  int eb = woff[wid] + v - s4;
  cbase[i0] = eb;
  cbase[i0 + 1] = eb + h0;
  cbase[i0 + 2] = eb + h0 + h1;
  cbase[i0 + 3] = eb + h0 + h1 + h2;
  __syncthreads();
  for (int i = tid; i < GCELLS; i += 1024) hist[i] = 0;
  __syncthreads();
  const size_t bo = (size_t)b * NN;
#pragma unroll
  for (int k = 0; k < 8; ++k) {
    int pos = cbase[cell[k]] + atomicAdd(&hist[cell[k]], 1);
    xs[bo + pos] = px[k];
    ys[bo + pos] = py[k];
    zs[bo + pos] = pz[k];
    io[bo + pos] = tid + (k << 10);
  }
}

// ---------------------------------------------------------------------------
// Pruned FPS: 512 threads/batch, 16 pts/thread (2 spatial groups of 8), all
// register-resident. Exact lazy update: a group is skipped only when the
// triangle inequality PROVES (with >=1e-3 absolute margin vs <=3e-6 fp32
// error) that min(stored,d2) == stored bitwise for every point in it.
// Selection comparator: (dist desc, orig idx asc) — matches np argmax.
// ---------------------------------------------------------------------------
__global__ __launch_bounds__(512, 1) void fps_kernel(
    const float* __restrict__ xyz, const float* __restrict__ xs,
    const float* __restrict__ ys, const float* __restrict__ zs,
    const int* __restrict__ io, float* __restrict__ newxyz) {
#pragma clang fp contract(off)
  const int b = blockIdx.x;
  const int tid = threadIdx.x;
  const int lane = tid & 63;
  const int wid = tid >> 6;
  const size_t bo = (size_t)b * NN;

  float X[2][8], Y[2][8], Z[2][8], D[2][8];
  int I[2][8];
  float GCX[2], GCY[2], GCZ[2], GR[2];
  float GV[2], GX[2], GY[2], GZ[2];
  int GI[2];
#pragma unroll
  for (int p = 0; p < 2; ++p) {
    float mx = 0.f, my = 0.f, mz = 0.f;
#pragma unroll
    for (int k = 0; k < 8; ++k) {
      int s = p * 4096 + tid * 8 + k;
      X[p][k] = xs[bo + s];
      Y[p][k] = ys[bo + s];
      Z[p][k] = zs[bo + s];
      I[p][k] = io[bo + s];
      D[p][k] = 1e10f;
      mx += X[p][k]; my += Y[p][k]; mz += Z[p][k];
    }
    mx *= 0.125f; my *= 0.125f; mz *= 0.125f;
    float r2m = 0.f;
#pragma unroll
    for (int k = 0; k < 8; ++k)
      r2m = fmaxf(r2m, d2_exact(X[p][k], Y[p][k], Z[p][k], mx, my, mz));
    GCX[p] = mx; GCY[p] = my; GCZ[p] = mz;
    GR[p] = __fmul_rn(sqrtf(r2m), 1.0001f) + 1e-6f;  // certified upper bound
    GV[p] = 1e10f;  // group max stored dist (exact); blocks skip until updated
    GI[p] = I[p][0]; GX[p] = X[p][0]; GY[p] = Y[p][0]; GZ[p] = Z[p][0];
  }

  __shared__ float vbuf[2][8];
  __shared__ int ibuf[2][8];
  __shared__ float cbuf[2][8][3];

  // initial center = original point 0
  const float* xb = xyz + (size_t)b * NN * 3;
  float cx = xb[0], cy = xb[1], cz = xb[2];
  if (tid == 0) {
    newxyz[(size_t)b * NPTS * 3 + 0] = cx;
    newxyz[(size_t)b * NPTS * 3 + 1] = cy;
    newxyz[(size_t)b * NPTS * 3 + 2] = cz;
  }

  for (int t = 1; t < NPTS; ++t) {
    const int par = t & 1;
#pragma unroll
    for (int p = 0; p < 2; ++p) {
      float d2c = d2_exact(GCX[p], GCY[p], GCZ[p], cx, cy, cz);
      float lb = sqrtf(d2c) - GR[p];
      float lbm = lb - 1e-3f;
      bool skip = (lb > 2e-3f) && (__fmul_rn(lbm, lbm) >= GV[p]);
      if (!skip) {
        float gv = -1.f; int gi = 0;
        float gx = 0.f, gy = 0.f, gz = 0.f;
#pragma unroll
        for (int k = 0; k < 8; ++k) {
          float d2 = d2_exact(X[p][k], Y[p][k], Z[p][k], cx, cy, cz);
          float nd = fminf(D[p][k], d2);
          D[p][k] = nd;
          bool c = (nd > gv) || (nd == gv && I[p][k] < gi);
          gv = c ? nd : gv; gi = c ? I[p][k] : gi;
          gx = c ? X[p][k] : gx; gy = c ? Y[p][k] : gy; gz = c ? Z[p][k] : gz;
        }
        GV[p] = gv; GI[p] = gi; GX[p] = gx; GY[p] = gy; GZ[p] = gz;
      }
    }
    // thread candidate
    float bv = GV[0]; int bi = GI[0];
    float bx = GX[0], by = GY[0], bz = GZ[0];
    {
      bool c = (GV[1] > bv) || (GV[1] == bv && GI[1] < bi);
      bv = c ? GV[1] : bv; bi = c ? GI[1] : bi;
      bx = c ? GX[1] : bx; by = c ? GY[1] : by; bz = c ? GZ[1] : bz;
    }
    // in-wave butterfly all-reduce on (value, orig idx)
    float rv = bv; int ri = bi;
    red_pair(rv, ri, dppf<0xB1>(rv), dppi<0xB1>(ri));
    red_pair(rv, ri, dppf<0x4E>(rv), dppi<0x4E>(ri));
    red_pair(rv, ri, dppf<0x141>(rv), dppi<0x141>(ri));
    red_pair(rv, ri, dppf<0x140>(rv), dppi<0x140>(ri));
    red_pair(rv, ri, __shfl_xor(rv, 16), __shfl_xor(ri, 16));
    red_pair(rv, ri, __shfl_xor(rv, 32), __shfl_xor(ri, 32));
    // unique owner (orig idx owned by exactly one thread) publishes
    if (bi == ri) {
      vbuf[par][wid] = rv;
      ibuf[par][wid] = ri;
      cbuf[par][wid][0] = bx; cbuf[par][wid][1] = by; cbuf[par][wid][2] = bz;
    }
    __syncthreads();
    // cross-wave: 8 partials, 3 DPP levels on (v, i, slot)
    int sl = lane & 7;
    float v2 = vbuf[par][sl];
    int i2 = ibuf[par][sl];
    int s2 = sl;
    red3(v2, i2, s2, dppf<0xB1>(v2), dppi<0xB1>(i2), dppi<0xB1>(s2));
    red3(v2, i2, s2, dppf<0x4E>(v2), dppi<0x4E>(i2), dppi<0x4E>(s2));
    red3(v2, i2, s2, dppf<0x141>(v2), dppi<0x141>(i2), dppi<0x141>(s2));
    cx = cbuf[par][s2][0]; cy = cbuf[par][s2][1]; cz = cbuf[par][s2][2];
    if (bi == i2) {  // unique global owner writes the center
      size_t o = ((size_t)b * NPTS + t) * 3;
      newxyz[o + 0] = bx; newxyz[o + 1] = by; newxyz[o + 2] = bz;
    }
    // one barrier/step: parity double-buffer (slot reuse at t+2 is ordered
    // by the t+1 barrier)
  }
}

// ---------------------------------------------------------------------------
// Fallback FPS (no workspace): R2's 1024-thread register kernel, unchanged.
// ---------------------------------------------------------------------------
__global__ __launch_bounds__(1024, 1) void fps_nosort_kernel(
    const float* __restrict__ xyz, float* __restrict__ newxyz) {
#pragma clang fp contract(off)
  const int b = blockIdx.x;
  const int tid = threadIdx.x;
  const int lane = tid & 63;
  const int wid = tid >> 6;
  const float* xb = xyz + (size_t)b * NN * 3;
  v2f x2[4], y2[4], z2[4], dd[4];
#pragma unroll
  for (int p = 0; p < 4; ++p) {
    int j0 = tid + ((2 * p) << 10);
    int j1 = tid + ((2 * p + 1) << 10);
    x2[p].x = xb[j0 * 3 + 0]; x2[p].y = xb[j1 * 3 + 0];
    y2[p].x = xb[j0 * 3 + 1]; y2[p].y = xb[j1 * 3 + 1];
    z2[p].x = xb[j0 * 3 + 2]; z2[p].y = xb[j1 * 3 + 2];
    dd[p].x = 1e10f; dd[p].y = 1e10f;
  }
  __shared__ float vbuf[2][16];
  __shared__ int ibuf[2][16];
  __shared__ float cbuf[2][16][3];
  float cx = xb[0], cy = xb[1], cz = xb[2];
  if (tid == 0) {
    newxyz[(size_t)b * NPTS * 3 + 0] = cx;
    newxyz[(size_t)b * NPTS * 3 + 1] = cy;
    newxyz[(size_t)b * NPTS * 3 + 2] = cz;
  }
  for (int t = 1; t < NPTS; ++t) {
    const int par = t & 1;
    float bv = -1.0f; int bi = 0;
    float bwx = 0.f, bwy = 0.f, bwz = 0.f;
#pragma unroll
    for (int p = 0; p < 4; ++p) {
      v2f dx = x2[p] - (v2f){cx, cx};
      v2f dy = y2[p] - (v2f){cy, cy};
      v2f dz = z2[p] - (v2f){cz, cz};
      v2f s = dx * dx + dy * dy + dz * dz;
      v2f nd;
      nd.x = fminf(dd[p].x, s.x);
      nd.y = fminf(dd[p].y, s.y);
      dd[p] = nd;
      { bool c = nd.x > bv;
        bv = c ? nd.x : bv; bi = c ? (tid + ((2 * p) << 10)) : bi;
        bwx = c ? x2[p].x : bwx; bwy = c ? y2[p].x : bwy; bwz = c ? z2[p].x : bwz; }
      { bool c = nd.y > bv;
        bv = c ? nd.y : bv; bi = c ? (tid + ((2 * p + 1) << 10)) : bi;
        bwx = c ? x2[p].y : bwx; bwy = c ? y2[p].y : bwy; bwz = c ? z2[p].y : bwz; }
    }
    red_pair(bv, bi, dppf<0xB1>(bv), dppi<0xB1>(bi));
    red_pair(bv, bi, dppf<0x4E>(bv), dppi<0x4E>(bi));
    red_pair(bv, bi, dppf<0x141>(bv), dppi<0x141>(bi));
    red_pair(bv, bi, dppf<0x140>(bv), dppi<0x140>(bi));
    red_pair(bv, bi, __shfl_xor(bv, 16), __shfl_xor(bi, 16));
    red_pair(bv, bi, __shfl_xor(bv, 32), __shfl_xor(bi, 32));
    if (tid == (bi & 1023)) {
      vbuf[par][wid] = bv; ibuf[par][wid] = bi;
      cbuf[par][wid][0] = bwx; cbuf[par][wid][1] = bwy; cbuf[par][wid][2] = bwz;
    }
    __syncthreads();
    float v2w = vbuf[par][lane & 15];
    int i2w = ibuf[par][lane & 15];
    red_pair(v2w, i2w, dppf<0xB1>(v2w), dppi<0xB1>(i2w));
    red_pair(v2w, i2w, dppf<0x4E>(v2w), dppi<0x4E>(i2w));
    red_pair(v2w, i2w, dppf<0x141>(v2w), dppi<0x141>(i2w));
    red_pair(v2w, i2w, dppf<0x140>(v2w), dppi<0x140>(i2w));
    const int slot = (i2w & 1023) >> 6;
    cx = cbuf[par][slot][0]; cy = cbuf[par][slot][1]; cz = cbuf[par][slot][2];
    if (tid == (i2w & 1023)) {
      size_t o = ((size_t)b * NPTS + t) * 3;
      newxyz[o + 0] = cx; newxyz[o + 1] = cy; newxyz[o + 2] = cz;
    }
  }
}

// ---------------------------------------------------------------------------
// Ball query: one wave per center; ballot scan in index order -> first 32 hits.
// ---------------------------------------------------------------------------
__global__ __launch_bounds__(256) void ballq_kernel(
    const float* __restrict__ xyz, const float* __restrict__ newxyz,
    int* __restrict__ bidx) {
  const int cid = blockIdx.x * 4 + (threadIdx.x >> 6);
  const int lane = threadIdx.x & 63;
  const int b = cid >> 11;
  const float* xb = xyz + (size_t)b * NN * 3;
  const float cx = newxyz[(size_t)cid * 3 + 0];
  const float cy = newxyz[(size_t)cid * 3 + 1];
  const float cz = newxyz[(size_t)cid * 3 + 2];
  int* ob = bidx + (size_t)cid * NSAMP;
  int total = 0;
  int first = -1;
  for (int c0 = 0; c0 < NN; c0 += 64) {
    int j = c0 + lane;
    float xx = xb[j * 3 + 0], yy = xb[j * 3 + 1], zz = xb[j * 3 + 2];
    float d2 = d2_exact(cx, cy, cz, xx, yy, zz);
    bool in = d2 <= 0.04f;
    unsigned long long m = __ballot(in);
    if (first < 0 && m) first = c0 + __builtin_ctzll(m);
    int pos = total + __popcll(m & ((1ull << lane) - 1ull));
    if (in && pos < NSAMP) ob[pos] = j;
    total += __popcll(m);
    if (total >= NSAMP) break;
  }
  if (total < NSAMP && lane < NSAMP - total) ob[total + lane] = first;
}

// ---------------------------------------------------------------------------
__global__ void tw_kernel(const float* __restrict__ W1, const float* __restrict__ W2,
                          const float* __restrict__ Wsa, float* __restrict__ w1t,
                          float* __restrict__ w2t, float* __restrict__ wsat) {
  int i = blockIdx.x * blockDim.x + threadIdx.x;
  if (i < CIN * NH1) w1t[i] = W1[(i % NH1) * CIN + (i / NH1)];
  if (i < NH1 * NH2) w2t[i] = W2[(i % NH2) * NH1 + (i / NH2)];
  if (i < NH2 * NOUTC) wsat[i] = Wsa[(i % NOUTC) * NH2 + (i / NOUTC)];
}

__global__ void tfeat_kernel(const float* __restrict__ feat, float* __restrict__ featT) {
  __shared__ float tile[32][33];
  const int b = blockIdx.z;
  const int n0 = blockIdx.x * 32, c0 = blockIdx.y * 32;
  const int tx = threadIdx.x, ty = threadIdx.y;
#pragma unroll
  for (int r = 0; r < 4; ++r)
    tile[ty + r * 8][tx] = feat[((size_t)b * NC + c0 + ty + r * 8) * NN + n0 + tx];
  __syncthreads();
#pragma unroll
  for (int r = 0; r < 4; ++r)
    featT[((size_t)b * NN + n0 + ty + r * 8) * NC + c0 + tx] = tile[tx][ty + r * 8];
}

// ---------------------------------------------------------------------------
// Fused gather + MLP(64,128) + maxpool + final linear, one block per center.
// ---------------------------------------------------------------------------
#define HS 36
__global__ __launch_bounds__(256) void mlp_kernel(
    const float* __restrict__ xyz, const float* __restrict__ fsrc,
    const float* __restrict__ newxyz, const int* __restrict__ bidx,
    const float* __restrict__ w1t, const float* __restrict__ b1,
    const float* __restrict__ w2t, const float* __restrict__ b2,
    const float* __restrict__ wsat, const float* __restrict__ bsa,
    float* __restrict__ out1, int useT) {
  __shared__ float h[CIN * HS];
  __shared__ float h1[NH1 * HS];
  __shared__ float pl[256];
  __shared__ float pooled[NH2];
  __shared__ int sidx[NSAMP];
  __shared__ float sc[3];
  const int cid = blockIdx.x;
  const int b = cid >> 11;
  const int s = cid & 2047;
  const int tid = threadIdx.x;
  if (tid < NSAMP) sidx[tid] = bidx[(size_t)cid * NSAMP + tid];
  if (tid < 3) sc[tid] = newxyz[(size_t)cid * 3 + tid];
  __syncthreads();
  {
    const int ss = tid >> 3, q = tid & 7;
    const int j = sidx[ss];
    if (useT) {
      const float4* fr = (const float4*)(fsrc + ((size_t)b * NN + j) * NC + q * 16);
#pragma unroll
      for (int u = 0; u < 4; ++u) {
        float4 v = fr[u];
        int c = 3 + q * 16 + u * 4;
        h[(c + 0) * HS + ss] = v.x;
        h[(c + 1) * HS + ss] = v.y;
        h[(c + 2) * HS + ss] = v.z;
        h[(c + 3) * HS + ss] = v.w;
      }
    } else {
      for (int u = 0; u < 16; ++u) {
        int c = q * 16 + u;
        h[(3 + c) * HS + ss] = fsrc[((size_t)b * NC + c) * NN + j];
      }
    }
    if (q == 0) {
      const float* pr = xyz + ((size_t)b * NN + j) * 3;
      h[0 * HS + ss] = pr[0] - sc[0];
      h[1 * HS + ss] = pr[1] - sc[1];
      h[2 * HS + ss] = pr[2] - sc[2];
    }
  }
  __syncthreads();
  {
    const int o = tid & 63, sg = tid >> 6;
    float acc[8];
    const float bb = b1[o];
#pragma unroll
    for (int i = 0; i < 8; ++i) acc[i] = bb;
    const float4* hb = (const float4*)&h[sg * 8];
    for (int k = 0; k < CIN; ++k) {
      float w = w1t[k * NH1 + o];
      float4 a = hb[k * (HS / 4) + 0];
      float4 c = hb[k * (HS / 4) + 1];
      acc[0] = fmaf(w, a.x, acc[0]); acc[1] = fmaf(w, a.y, acc[1]);
      acc[2] = fmaf(w, a.z, acc[2]); acc[3] = fmaf(w, a.w, acc[3]);
      acc[4] = fmaf(w, c.x, acc[4]); acc[5] = fmaf(w, c.y, acc[5]);
      acc[6] = fmaf(w, c.z, acc[6]); acc[7] = fmaf(w, c.w, acc[7]);
    }
#pragma unroll
    for (int i = 0; i < 8; ++i) h1[o * HS + sg * 8 + i] = fmaxf(acc[i], 0.0f);
  }
  __syncthreads();
  {
    const int o = tid & 127, sg = tid >> 7;
    float acc[16];
    const float bb = b2[o];
#pragma unroll
    for (int i = 0; i < 16; ++i) acc[i] = bb;
    const float4* hb = (const float4*)&h1[sg * 16];
    for (int k = 0; k < NH1; ++k) {
      float w = w2t[k * NH2 + o];
#pragma unroll
      for (int u = 0; u < 4; ++u) {
        float4 a = hb[k * (HS / 4) + u];
        acc[u * 4 + 0] = fmaf(w, a.x, acc[u * 4 + 0]);
        acc[u * 4 + 1] = fmaf(w, a.y, acc[u * 4 + 1]);
        acc[u * 4 + 2] = fmaf(w, a.z, acc[u * 4 + 2]);
        acc[u * 4 + 3] = fmaf(w, a.w, acc[u * 4 + 3]);
      }
    }
    float pm = acc[0];
#pragma unroll
    for (int i = 1; i < 16; ++i) pm = fmaxf(pm, acc[i]);
    pl[sg * 128 + o] = pm;
  }
  __syncthreads();
  if (tid < NH2) pooled[tid] = fmaxf(fmaxf(pl[tid], pl[128 + tid]), 0.0f);
  __syncthreads();
  if (tid < NOUTC) {
    float acc = bsa[tid];
    for (int k = 0; k < NH2; ++k) acc = fmaf(pooled[k], wsat[k * NOUTC + tid], acc);
    out1[((size_t)b * NOUTC + tid) * NPTS + s] = acc;
  }
}

extern "C" void kernel_launch(void* const* d_in, const int* in_sizes, int n_in,
                              void* d_out, int out_size, void* d_ws, size_t ws_size,
                              hipStream_t stream) {
  const float* xyz = (const float*)d_in[0];
  const float* feat = (const float*)d_in[1];
  const float* W1 = (const float*)d_in[2];
  const float* b1 = (const float*)d_in[3];
  const float* W2 = (const float*)d_in[4];
  const float* b2 = (const float*)d_in[5];
  const float* Wsa = (const float*)d_in[6];
  const float* bsa = (const float*)d_in[7];
  float* out = (float*)d_out;
  float* newxyz = out;                       // (B, NPTS, 3)
  float* out1 = out + (size_t)NB * NPTS * 3; // (B, OUT, NPTS)

  const size_t sort_f = (size_t)NB * NN * 4;  // xs, ys, zs, io
  const size_t small_f = (size_t)CIN * NH1 + NH1 * NH2 + NH2 * NOUTC +
                         (size_t)NB * NPTS * NSAMP;
  const size_t featT_f = (size_t)NB * NN * NC;

  float* ws = (float*)d_ws;
  bool useSort = ws_size >= (sort_f + small_f) * 4;
  bool useT = ws_size >= (sort_f + small_f + featT_f) * 4;

  float* xs = ws;
  float* ysr = xs + (size_t)NB * NN;
  float* zsr = ysr + (size_t)NB * NN;
  int* iosr = (int*)(zsr + (size_t)NB * NN);
  float* base2 = useSort ? (ws + sort_f) : ws;
  float* w1t = base2;
  float* w2t = w1t + CIN * NH1;
  float* wsat = w2t + NH1 * NH2;
  int* bidx = (int*)(wsat + NH2 * NOUTC);
  float* featT = (float*)(bidx + (size_t)NB * NPTS * NSAMP);

  tw_kernel<<<64, 256, 0, stream>>>(W1, W2, Wsa, w1t, w2t, wsat);
  if (useT)
    tfeat_kernel<<<dim3(NN / 32, NC / 32, NB), dim3(32, 8), 0, stream>>>(feat, featT);
  if (useSort) {
    sort_kernel<<<NB, 1024, 0, stream>>>(xyz, xs, ysr, zsr, iosr);
    fps_kernel<<<NB, 512, 0, stream>>>(xyz, xs, ysr, zsr, iosr, newxyz);
  } else {
    fps_nosort_kernel<<<NB, 1024, 0, stream>>>(xyz, newxyz);
  }
  ballq_kernel<<<NB * NPTS / 4, 256, 0, stream>>>(xyz, newxyz, bidx);
  mlp_kernel<<<NB * NPTS, 256, 0, stream>>>(xyz, useT ? featT : feat, newxyz, bidx,
                                            w1t, b1, w2t, b2, wsat, bsa, out1,
                                            (int)useT);
}

// Round 4
// 4095.805 us; speedup vs baseline: 1.0175x; 1.0175x over previous
//
#include <hip/hip_runtime.h>
#include <cstdint>
#include <cstddef>

#define NB 4
#define NN 8192
#define NPTS 2048
#define NSAMP 32
#define NC 128
#define CIN 131      // 3 + NC
#define NH1 64
#define NH2 128
#define NOUTC 128
#define GCELLS 4096  // 16x16x16 morton grid

typedef float v2f __attribute__((ext_vector_type(2)));

// Exact (numpy-order, contraction-free) squared distance:
// ((dx*dx + dy*dy) + dz*dz), round-to-nearest each op, no FMA.
__device__ __forceinline__ float d2_exact(float ax, float ay, float az,
                                          float bx, float by, float bz) {
  float dx = ax - bx, dy = ay - by, dz = az - bz;
  return __fadd_rn(__fadd_rn(__fmul_rn(dx, dx), __fmul_rn(dy, dy)),
                   __fmul_rn(dz, dz));
}

// ---- DPP cross-lane (VALU, no LDS). 0xB1=xor1 0x4E=xor2 0x141=xor7 0x140=xor15
#if __has_builtin(__builtin_amdgcn_mov_dpp)
template <int CTRL>
__device__ __forceinline__ float dppf(float v) {
  return __int_as_float(
      __builtin_amdgcn_mov_dpp(__float_as_int(v), CTRL, 0xF, 0xF, true));
}
template <int CTRL>
__device__ __forceinline__ int dppi(int v) {
  return __builtin_amdgcn_mov_dpp(v, CTRL, 0xF, 0xF, true);
}
#else
template <int CTRL>
__device__ __forceinline__ float dppf(float v) {
  const int m = (CTRL == 0xB1) ? 1 : (CTRL == 0x4E) ? 2 : (CTRL == 0x141) ? 7 : 15;
  return __shfl_xor(v, m);
}
template <int CTRL>
__device__ __forceinline__ int dppi(int v) {
  const int m = (CTRL == 0xB1) ? 1 : (CTRL == 0x4E) ? 2 : (CTRL == 0x141) ? 7 : 15;
  return __shfl_xor(v, m);
}
#endif

// argmax combine: larger value wins; on equal value, smaller index wins
__device__ __forceinline__ void red_pair(float& bv, int& bi, float ov, int oi) {
  bool t = (ov > bv) || (ov == bv && oi < bi);
  bv = t ? ov : bv;
  bi = t ? oi : bi;
}
// same comparator, carrying coords through row-local DPP
template <int CTRL>
__device__ __forceinline__ void red5(float& v, int& i, float& x, float& y,
                                     float& z) {
  float ov = dppf<CTRL>(v);
  int oi = dppi<CTRL>(i);
  float ox = dppf<CTRL>(x), oy = dppf<CTRL>(y), oz = dppf<CTRL>(z);
  bool t = (ov > v) || (ov == v && oi < i);
  v = t ? ov : v; i = t ? oi : i;
  x = t ? ox : x; y = t ? oy : y; z = t ? oz : z;
}

// ---------------------------------------------------------------------------
// Spatial counting sort into 16^3 morton cells (one block per batch).
// Order within a cell is nondeterministic (LDS atomics) — harmless: FPS
// selection is order-independent (total order on (value, orig_idx)).
// ---------------------------------------------------------------------------
__device__ __forceinline__ int spread3(int v) {  // 4 bits -> every 3rd bit
  return (v & 1) | ((v & 2) << 2) | ((v & 4) << 4) | ((v & 8) << 6);
}

__global__ __launch_bounds__(1024, 1) void sort_kernel(
    const float* __restrict__ xyz, float* __restrict__ xs,
    float* __restrict__ ys, float* __restrict__ zs, int* __restrict__ io) {
  __shared__ int hist[GCELLS];
  __shared__ int cbase[GCELLS];
  __shared__ int wtot[16];
  __shared__ int woff[16];
  const int b = blockIdx.x;
  const int tid = threadIdx.x;
  const int lane = tid & 63;
  const int wid = tid >> 6;
  const float* xb = xyz + (size_t)b * NN * 3;
  for (int i = tid; i < GCELLS; i += 1024) hist[i] = 0;
  __syncthreads();
  int cell[8];
  float px[8], py[8], pz[8];
#pragma unroll
  for (int k = 0; k < 8; ++k) {
    int j = tid + (k << 10);
    float x = xb[j * 3 + 0], y = xb[j * 3 + 1], z = xb[j * 3 + 2];
    px[k] = x; py[k] = y; pz[k] = z;
    int cx = min(15, max(0, (int)(x * 16.0f)));
    int cy = min(15, max(0, (int)(y * 16.0f)));
    int cz = min(15, max(0, (int)(z * 16.0f)));
    cell[k] = spread3(cx) | (spread3(cy) << 1) | (spread3(cz) << 2);
    atomicAdd(&hist[cell[k]], 1);
  }
  __syncthreads();
  const int i0 = tid * 4;
  int h0 = hist[i0], h1 = hist[i0 + 1], h2 = hist[i0 + 2], h3 = hist[i0 + 3];
  int s4 = h0 + h1 + h2 + h3;
  int v = s4;
#pragma unroll
  for (int d = 1; d < 64; d <<= 1) {
    int o = __shfl_up(v, d);
    if (lane >= d) v += o;
  }
  if (lane == 63) wtot[wid] = v;
  __syncthreads();
  if (tid < 16) {
    int acc = 0;
    for (int w = 0; w < 16; ++w) {
      if (w == tid) woff[tid] = acc;
      acc += wtot[w];
    }
  }
  __syncthreads();
  int eb = woff[wid] + v - s4;
  cbase[i0] = eb;
  cbase[i0 + 1] = eb + h0;
  cbase[i0 + 2] = eb + h0 + h1;
  cbase[i0 + 3] = eb + h0 + h1 + h2;
  __syncthreads();
  for (int i = tid; i < GCELLS; i += 1024) hist[i] = 0;
  __syncthreads();
  const size_t bo = (size_t)b * NN;
#pragma unroll
  for (int k = 0; k < 8; ++k) {
    int pos = cbase[cell[k]] + atomicAdd(&hist[cell[k]], 1);
    xs[bo + pos] = px[k];
    ys[bo + pos] = py[k];
    zs[bo + pos] = zs == nullptr ? 0.f : pz[k];
    io[bo + pos] = tid + (k << 10);
  }
}

// ---------------------------------------------------------------------------
// Pruned FPS v2: 1024 threads/batch, ONE spatial group of 8 sorted points per
// thread (register-resident). Exact lazy update (certified 2e-3 margin vs
// <=1e-5 fp32 error). Wave-candidate caching: a wave re-reduces only when a
// member thread updated (values only decrease -> cached max stays exact).
// One barrier/step; 16-slot cross-wave reduce via row-local DPP carrying
// (v, idx, x, y, z). Comparator everywhere: (dist desc, orig idx asc).
// ---------------------------------------------------------------------------
__global__ __launch_bounds__(1024, 1) void fps_kernel(
    const float* __restrict__ xyz, const float* __restrict__ xs,
    const float* __restrict__ ys, const float* __restrict__ zs,
    const int* __restrict__ io, float* __restrict__ newxyz) {
#pragma clang fp contract(off)
  const int b = blockIdx.x;
  const int tid = threadIdx.x;
  const int lane = tid & 63;
  const int wid = tid >> 6;
  const size_t bo = (size_t)b * NN;

  float X[8], Y[8], Z[8], D[8];
  int I[8];
  float gcx, gcy, gcz, gr;
  {
    float mx = 0.f, my = 0.f, mz = 0.f;
#pragma unroll
    for (int k = 0; k < 8; ++k) {
      int s = tid * 8 + k;
      X[k] = xs[bo + s];
      Y[k] = ys[bo + s];
      Z[k] = zs[bo + s];
      I[k] = io[bo + s];
      D[k] = 1e30f;
      mx += X[k]; my += Y[k]; mz += Z[k];
    }
    mx *= 0.125f; my *= 0.125f; mz *= 0.125f;
    float r2m = 0.f;
#pragma unroll
    for (int k = 0; k < 8; ++k)
      r2m = fmaxf(r2m, d2_exact(X[k], Y[k], Z[k], mx, my, mz));
    gcx = mx; gcy = my; gcz = mz;
    gr = __fmul_rn(sqrtf(r2m), 1.0001f) + 1e-6f;
  }
  float gv = -1.0f;          // thread candidate value (max stored dist)
  int gidx = 0x3fffffff;     // thread candidate orig idx
  float bwx = 0.f, bwy = 0.f, bwz = 0.f;  // its coords
  float T = 3e38f;           // skip threshold: skip iff d2(gc,c) >= T
  float cv = -1.0f; int ci = 0x3fffffff;  // wave cache
  float ccx = 0.f, ccy = 0.f, ccz = 0.f;

  __shared__ float sv[2][16];
  __shared__ int si[2][16];
  __shared__ float sxx[2][16], syy[2][16], szz[2][16];

  const float* xb = xyz + (size_t)b * NN * 3;
  float cx = xb[0], cy = xb[1], cz = xb[2];
  if (tid == 0) {
    newxyz[(size_t)b * NPTS * 3 + 0] = cx;
    newxyz[(size_t)b * NPTS * 3 + 1] = cy;
    newxyz[(size_t)b * NPTS * 3 + 2] = cz;
  }

  for (int t = 1; t < NPTS; ++t) {
    const int par = t & 1;
    const float d2c = d2_exact(gcx, gcy, gcz, cx, cy, cz);
    const bool dirty = d2c < T;
    if (dirty) {  // whole-wave SIMT body; execz-skipped on clean waves
      float nv = -1.0f; int ni = 0x3fffffff;
      float nx = 0.f, ny = 0.f, nz = 0.f;
#pragma unroll
      for (int k = 0; k < 8; ++k) {
        float d2 = d2_exact(X[k], Y[k], Z[k], cx, cy, cz);
        float nd = fminf(D[k], d2);
        D[k] = nd;
        bool c = (nd > nv) || (nd == nv && I[k] < ni);
        nv = c ? nd : nv; ni = c ? I[k] : ni;
        nx = c ? X[k] : nx; ny = c ? Y[k] : ny; nz = c ? Z[k] : nz;
      }
      gv = nv; gidx = ni; bwx = nx; bwy = ny; bwz = nz;
      float s = __fadd_rn(__fmul_rn(sqrtf(nv), 1.0001f), __fadd_rn(gr, 2e-3f));
      T = __fmul_rn(__fmul_rn(s, s), 1.0001f);
    }
    if (__ballot(dirty) != 0ull) {  // wave candidate invalid -> re-reduce
      float rv = gv; int ri = gidx;
      red_pair(rv, ri, dppf<0xB1>(rv), dppi<0xB1>(ri));
      red_pair(rv, ri, dppf<0x4E>(rv), dppi<0x4E>(ri));
      red_pair(rv, ri, dppf<0x141>(rv), dppi<0x141>(ri));
      red_pair(rv, ri, dppf<0x140>(rv), dppi<0x140>(ri));
      red_pair(rv, ri, __shfl_xor(rv, 16), __shfl_xor(ri, 16));
      red_pair(rv, ri, __shfl_xor(rv, 32), __shfl_xor(ri, 32));
      unsigned long long m = __ballot(gidx == ri);  // exactly one lane set
      int owner = (int)__builtin_ctzll(m);
      cv = rv; ci = ri;
      ccx = __shfl(bwx, owner);
      ccy = __shfl(bwy, owner);
      ccz = __shfl(bwz, owner);
    }
    if (lane == 0) {
      sv[par][wid] = cv; si[par][wid] = ci;
      sxx[par][wid] = ccx; syy[par][wid] = ccy; szz[par][wid] = ccz;
    }
    __syncthreads();
    const int sl = lane & 15;
    float v = sv[par][sl];
    int i = si[par][sl];
    float xx = sxx[par][sl], yy = syy[par][sl], zz = szz[par][sl];
    red5<0xB1>(v, i, xx, yy, zz);
    red5<0x4E>(v, i, xx, yy, zz);
    red5<0x141>(v, i, xx, yy, zz);
    red5<0x140>(v, i, xx, yy, zz);
    cx = xx; cy = yy; cz = zz;
    if (gidx == i) {  // unique global owner writes the center
      size_t o = ((size_t)b * NPTS + t) * 3;
      newxyz[o + 0] = xx; newxyz[o + 1] = yy; newxyz[o + 2] = zz;
    }
    // one barrier/step: parity slots; reuse at t+2 ordered by t+1's barrier
  }
}

// ---------------------------------------------------------------------------
// Fallback FPS (no workspace): R2's 1024-thread register kernel.
// ---------------------------------------------------------------------------
__global__ __launch_bounds__(1024, 1) void fps_nosort_kernel(
    const float* __restrict__ xyz, float* __restrict__ newxyz) {
#pragma clang fp contract(off)
  const int b = blockIdx.x;
  const int tid = threadIdx.x;
  const int lane = tid & 63;
  const int wid = tid >> 6;
  const float* xb = xyz + (size_t)b * NN * 3;
  v2f x2[4], y2[4], z2[4], dd[4];
#pragma unroll
  for (int p = 0; p < 4; ++p) {
    int j0 = tid + ((2 * p) << 10);
    int j1 = tid + ((2 * p + 1) << 10);
    x2[p].x = xb[j0 * 3 + 0]; x2[p].y = xb[j1 * 3 + 0];
    y2[p].x = xb[j0 * 3 + 1]; y2[p].y = xb[j1 * 3 + 1];
    z2[p].x = xb[j0 * 3 + 2]; z2[p].y = xb[j1 * 3 + 2];
    dd[p].x = 1e10f; dd[p].y = 1e10f;
  }
  __shared__ float vbuf[2][16];
  __shared__ int ibuf[2][16];
  __shared__ float cbuf[2][16][3];
  float cx = xb[0], cy = xb[1], cz = xb[2];
  if (tid == 0) {
    newxyz[(size_t)b * NPTS * 3 + 0] = cx;
    newxyz[(size_t)b * NPTS * 3 + 1] = cy;
    newxyz[(size_t)b * NPTS * 3 + 2] = cz;
  }
  for (int t = 1; t < NPTS; ++t) {
    const int par = t & 1;
    float bv = -1.0f; int bi = 0;
    float bwx = 0.f, bwy = 0.f, bwz = 0.f;
#pragma unroll
    for (int p = 0; p < 4; ++p) {
      v2f dx = x2[p] - (v2f){cx, cx};
      v2f dy = y2[p] - (v2f){cy, cy};
      v2f dz = z2[p] - (v2f){cz, cz};
      v2f s = dx * dx + dy * dy + dz * dz;
      v2f nd;
      nd.x = fminf(dd[p].x, s.x);
      nd.y = fminf(dd[p].y, s.y);
      dd[p] = nd;
      { bool c = nd.x > bv;
        bv = c ? nd.x : bv; bi = c ? (tid + ((2 * p) << 10)) : bi;
        bwx = c ? x2[p].x : bwx; bwy = c ? y2[p].x : bwy; bwz = c ? z2[p].x : bwz; }
      { bool c = nd.y > bv;
        bv = c ? nd.y : bv; bi = c ? (tid + ((2 * p + 1) << 10)) : bi;
        bwx = c ? x2[p].y : bwx; bwy = c ? y2[p].y : bwy; bwz = c ? z2[p].y : bwz; }
    }
    red_pair(bv, bi, dppf<0xB1>(bv), dppi<0xB1>(bi));
    red_pair(bv, bi, dppf<0x4E>(bv), dppi<0x4E>(bi));
    red_pair(bv, bi, dppf<0x141>(bv), dppi<0x141>(bi));
    red_pair(bv, bi, dppf<0x140>(bv), dppi<0x140>(bi));
    red_pair(bv, bi, __shfl_xor(bv, 16), __shfl_xor(bi, 16));
    red_pair(bv, bi, __shfl_xor(bv, 32), __shfl_xor(bi, 32));
    if (tid == (bi & 1023)) {
      vbuf[par][wid] = bv; ibuf[par][wid] = bi;
      cbuf[par][wid][0] = bwx; cbuf[par][wid][1] = bwy; cbuf[par][wid][2] = bwz;
    }
    __syncthreads();
    float v2w = vbuf[par][lane & 15];
    int i2w = ibuf[par][lane & 15];
    red_pair(v2w, i2w, dppf<0xB1>(v2w), dppi<0xB1>(i2w));
    red_pair(v2w, i2w, dppf<0x4E>(v2w), dppi<0x4E>(i2w));
    red_pair(v2w, i2w, dppf<0x141>(v2w), dppi<0x141>(i2w));
    red_pair(v2w, i2w, dppf<0x140>(v2w), dppi<0x140>(i2w));
    const int slot = (i2w & 1023) >> 6;
    cx = cbuf[par][slot][0]; cy = cbuf[par][slot][1]; cz = cbuf[par][slot][2];
    if (tid == (i2w & 1023)) {
      size_t o = ((size_t)b * NPTS + t) * 3;
      newxyz[o + 0] = cx; newxyz[o + 1] = cy; newxyz[o + 2] = cz;
    }
  }
}

// ---------------------------------------------------------------------------
// Ball query: one wave per center; ballot scan in index order -> first 32 hits.
// ---------------------------------------------------------------------------
__global__ __launch_bounds__(256) void ballq_kernel(
    const float* __restrict__ xyz, const float* __restrict__ newxyz,
    int* __restrict__ bidx) {
  const int cid = blockIdx.x * 4 + (threadIdx.x >> 6);
  const int lane = threadIdx.x & 63;
  const int b = cid >> 11;
  const float* xb = xyz + (size_t)b * NN * 3;
  const float cx = newxyz[(size_t)cid * 3 + 0];
  const float cy = newxyz[(size_t)cid * 3 + 1];
  const float cz = newxyz[(size_t)cid * 3 + 2];
  int* ob = bidx + (size_t)cid * NSAMP;
  int total = 0;
  int first = -1;
  for (int c0 = 0; c0 < NN; c0 += 64) {
    int j = c0 + lane;
    float xx = xb[j * 3 + 0], yy = xb[j * 3 + 1], zz = xb[j * 3 + 2];
    float d2 = d2_exact(cx, cy, cz, xx, yy, zz);
    bool in = d2 <= 0.04f;
    unsigned long long m = __ballot(in);
    if (first < 0 && m) first = c0 + __builtin_ctzll(m);
    int pos = total + __popcll(m & ((1ull << lane) - 1ull));
    if (in && pos < NSAMP) ob[pos] = j;
    total += __popcll(m);
    if (total >= NSAMP) break;
  }
  if (total < NSAMP && lane < NSAMP - total) ob[total + lane] = first;
}

// ---------------------------------------------------------------------------
__global__ void tw_kernel(const float* __restrict__ W1, const float* __restrict__ W2,
                          const float* __restrict__ Wsa, float* __restrict__ w1t,
                          float* __restrict__ w2t, float* __restrict__ wsat) {
  int i = blockIdx.x * blockDim.x + threadIdx.x;
  if (i < CIN * NH1) w1t[i] = W1[(i % NH1) * CIN + (i / NH1)];
  if (i < NH1 * NH2) w2t[i] = W2[(i % NH2) * NH1 + (i / NH2)];
  if (i < NH2 * NOUTC) wsat[i] = Wsa[(i % NOUTC) * NH2 + (i / NOUTC)];
}

__global__ void tfeat_kernel(const float* __restrict__ feat, float* __restrict__ featT) {
  __shared__ float tile[32][33];
  const int b = blockIdx.z;
  const int n0 = blockIdx.x * 32, c0 = blockIdx.y * 32;
  const int tx = threadIdx.x, ty = threadIdx.y;
#pragma unroll
  for (int r = 0; r < 4; ++r)
    tile[ty + r * 8][tx] = feat[((size_t)b * NC + c0 + ty + r * 8) * NN + n0 + tx];
  __syncthreads();
#pragma unroll
  for (int r = 0; r < 4; ++r)
    featT[((size_t)b * NN + n0 + ty + r * 8) * NC + c0 + tx] = tile[tx][ty + r * 8];
}

// ---------------------------------------------------------------------------
// Fused gather + MLP(64,128) + maxpool + final linear, one block per center.
// ---------------------------------------------------------------------------
#define HS 36
__global__ __launch_bounds__(256) void mlp_kernel(
    const float* __restrict__ xyz, const float* __restrict__ fsrc,
    const float* __restrict__ newxyz, const int* __restrict__ bidx,
    const float* __restrict__ w1t, const float* __restrict__ b1,
    const float* __restrict__ w2t, const float* __restrict__ b2,
    const float* __restrict__ wsat, const float* __restrict__ bsa,
    float* __restrict__ out1, int useT) {
  __shared__ float h[CIN * HS];
  __shared__ float h1[NH1 * HS];
  __shared__ float pl[256];
  __shared__ float pooled[NH2];
  __shared__ int sidx[NSAMP];
  __shared__ float sc[3];
  const int cid = blockIdx.x;
  const int b = cid >> 11;
  const int s = cid & 2047;
  const int tid = threadIdx.x;
  if (tid < NSAMP) sidx[tid] = bidx[(size_t)cid * NSAMP + tid];
  if (tid < 3) sc[tid] = newxyz[(size_t)cid * 3 + tid];
  __syncthreads();
  {
    const int ss = tid >> 3, q = tid & 7;
    const int j = sidx[ss];
    if (useT) {
      const float4* fr = (const float4*)(fsrc + ((size_t)b * NN + j) * NC + q * 16);
#pragma unroll
      for (int u = 0; u < 4; ++u) {
        float4 v = fr[u];
        int c = 3 + q * 16 + u * 4;
        h[(c + 0) * HS + ss] = v.x;
        h[(c + 1) * HS + ss] = v.y;
        h[(c + 2) * HS + ss] = v.z;
        h[(c + 3) * HS + ss] = v.w;
      }
    } else {
      for (int u = 0; u < 16; ++u) {
        int c = q * 16 + u;
        h[(3 + c) * HS + ss] = fsrc[((size_t)b * NC + c) * NN + j];
      }
    }
    if (q == 0) {
      const float* pr = xyz + ((size_t)b * NN + j) * 3;
      h[0 * HS + ss] = pr[0] - sc[0];
      h[1 * HS + ss] = pr[1] - sc[1];
      h[2 * HS + ss] = pr[2] - sc[2];
    }
  }
  __syncthreads();
  {
    const int o = tid & 63, sg = tid >> 6;
    float acc[8];
    const float bb = b1[o];
#pragma unroll
    for (int i = 0; i < 8; ++i) acc[i] = bb;
    const float4* hb = (const float4*)&h[sg * 8];
    for (int k = 0; k < CIN; ++k) {
      float w = w1t[k * NH1 + o];
      float4 a = hb[k * (HS / 4) + 0];
      float4 c = hb[k * (HS / 4) + 1];
      acc[0] = fmaf(w, a.x, acc[0]); acc[1] = fmaf(w, a.y, acc[1]);
      acc[2] = fmaf(w, a.z, acc[2]); acc[3] = fmaf(w, a.w, acc[3]);
      acc[4] = fmaf(w, c.x, acc[4]); acc[5] = fmaf(w, c.y, acc[5]);
      acc[6] = fmaf(w, c.z, acc[6]); acc[7] = fmaf(w, c.w, acc[7]);
    }
#pragma unroll
    for (int i = 0; i < 8; ++i) h1[o * HS + sg * 8 + i] = fmaxf(acc[i], 0.0f);
  }
  __syncthreads();
  {
    const int o = tid & 127, sg = tid >> 7;
    float acc[16];
    const float bb = b2[o];
#pragma unroll
    for (int i = 0; i < 16; ++i) acc[i] = bb;
    const float4* hb = (const float4*)&h1[sg * 16];
    for (int k = 0; k < NH1; ++k) {
      float w = w2t[k * NH2 + o];
#pragma unroll
      for (int u = 0; u < 4; ++u) {
        float4 a = hb[k * (HS / 4) + u];
        acc[u * 4 + 0] = fmaf(w, a.x, acc[u * 4 + 0]);
        acc[u * 4 + 1] = fmaf(w, a.y, acc[u * 4 + 1]);
        acc[u * 4 + 2] = fmaf(w, a.z, acc[u * 4 + 2]);
        acc[u * 4 + 3] = fmaf(w, a.w, acc[u * 4 + 3]);
      }
    }
    float pm = acc[0];
#pragma unroll
    for (int i = 1; i < 16; ++i) pm = fmaxf(pm, acc[i]);
    pl[sg * 128 + o] = pm;
  }
  __syncthreads();
  if (tid < NH2) pooled[tid] = fmaxf(fmaxf(pl[tid], pl[128 + tid]), 0.0f);
  __syncthreads();
  if (tid < NOUTC) {
    float acc = bsa[tid];
    for (int k = 0; k < NH2; ++k) acc = fmaf(pooled[k], wsat[k * NOUTC + tid], acc);
    out1[((size_t)b * NOUTC + tid) * NPTS + s] = acc;
  }
}

extern "C" void kernel_launch(void* const* d_in, const int* in_sizes, int n_in,
                              void* d_out, int out_size, void* d_ws, size_t ws_size,
                              hipStream_t stream) {
  const float* xyz = (const float*)d_in[0];
  const float* feat = (const float*)d_in[1];
  const float* W1 = (const float*)d_in[2];
  const float* b1 = (const float*)d_in[3];
  const float* W2 = (const float*)d_in[4];
  const float* b2 = (const float*)d_in[5];
  const float* Wsa = (const float*)d_in[6];
  const float* bsa = (const float*)d_in[7];
  float* out = (float*)d_out;
  float* newxyz = out;                       // (B, NPTS, 3)
  float* out1 = out + (size_t)NB * NPTS * 3; // (B, OUT, NPTS)

  const size_t sort_f = (size_t)NB * NN * 4;  // xs, ys, zs, io
  const size_t small_f = (size_t)CIN * NH1 + NH1 * NH2 + NH2 * NOUTC +
                         (size_t)NB * NPTS * NSAMP;
  const size_t featT_f = (size_t)NB * NN * NC;

  float* ws = (float*)d_ws;
  bool useSort = ws_size >= (sort_f + small_f) * 4;
  bool useT = ws_size >= (sort_f + small_f + featT_f) * 4;

  float* xs = ws;
  float* ysr = xs + (size_t)NB * NN;
  float* zsr = ysr + (size_t)NB * NN;
  int* iosr = (int*)(zsr + (size_t)NB * NN);
  float* base2 = useSort ? (ws + sort_f) : ws;
  float* w1t = base2;
  float* w2t = w1t + CIN * NH1;
  float* wsat = w2t + NH1 * NH2;
  int* bidx = (int*)(wsat + NH2 * NOUTC);
  float* featT = (float*)(bidx + (size_t)NB * NPTS * NSAMP);

  tw_kernel<<<64, 256, 0, stream>>>(W1, W2, Wsa, w1t, w2t, wsat);
  if (useT)
    tfeat_kernel<<<dim3(NN / 32, NC / 32, NB), dim3(32, 8), 0, stream>>>(feat, featT);
  if (useSort) {
    sort_kernel<<<NB, 1024, 0, stream>>>(xyz, xs, ysr, zsr, iosr);
    fps_kernel<<<NB, 1024, 0, stream>>>(xyz, xs, ysr, zsr, iosr, newxyz);
  } else {
    fps_nosort_kernel<<<NB, 1024, 0, stream>>>(xyz, newxyz);
  }
  ballq_kernel<<<NB * NPTS / 4, 256, 0, stream>>>(xyz, newxyz, bidx);
  mlp_kernel<<<NB * NPTS, 256, 0, stream>>>(xyz, useT ? featT : feat, newxyz, bidx,
                                            w1t, b1, w2t, b2, wsat, bsa, out1,
                                            (int)useT);
}

// Round 5
// 3906.403 us; speedup vs baseline: 1.0669x; 1.0485x over previous
//
#include <hip/hip_runtime.h>
#include <cstdint>
#include <cstddef>

#define NB 4
#define NN 8192
#define NPTS 2048
#define NSAMP 32
#define NC 128
#define CIN 131      // 3 + NC
#define NH1 64
#define NH2 128
#define NOUTC 128
#define GCELLS 4096  // 16x16x16 morton grid

typedef float v2f __attribute__((ext_vector_type(2)));

// Exact (numpy-order, contraction-free) squared distance:
// ((dx*dx + dy*dy) + dz*dz), round-to-nearest each op, no FMA.
__device__ __forceinline__ float d2_exact(float ax, float ay, float az,
                                          float bx, float by, float bz) {
  float dx = ax - bx, dy = ay - by, dz = az - bz;
  return __fadd_rn(__fadd_rn(__fmul_rn(dx, dx), __fmul_rn(dy, dy)),
                   __fmul_rn(dz, dz));
}

// ---- DPP cross-lane (VALU, no LDS). 0xB1=xor1 0x4E=xor2 0x141=xor7(row half
// mirror) 0x140=xor15(row mirror) — {1,2,7,15} spans 4 bits -> 16-lane allreduce.
#if __has_builtin(__builtin_amdgcn_mov_dpp)
template <int CTRL>
__device__ __forceinline__ float dppf(float v) {
  return __int_as_float(
      __builtin_amdgcn_mov_dpp(__float_as_int(v), CTRL, 0xF, 0xF, true));
}
template <int CTRL>
__device__ __forceinline__ int dppi(int v) {
  return __builtin_amdgcn_mov_dpp(v, CTRL, 0xF, 0xF, true);
}
#else
template <int CTRL>
__device__ __forceinline__ float dppf(float v) {
  const int m = (CTRL == 0xB1) ? 1 : (CTRL == 0x4E) ? 2 : (CTRL == 0x141) ? 7 : 15;
  return __shfl_xor(v, m);
}
template <int CTRL>
__device__ __forceinline__ int dppi(int v) {
  const int m = (CTRL == 0xB1) ? 1 : (CTRL == 0x4E) ? 2 : (CTRL == 0x141) ? 7 : 15;
  return __shfl_xor(v, m);
}
#endif

// total order: (value desc, index asc). distinct points => strict.
__device__ __forceinline__ bool tgt(float av, int ai, float bv, int bi) {
  return (av > bv) || (av == bv && ai < bi);
}

// argmax combine for (v,i) pairs (fallback kernel)
__device__ __forceinline__ void red_pair(float& bv, int& bi, float ov, int oi) {
  bool t = tgt(ov, oi, bv, bi);
  bv = t ? ov : bv;
  bi = t ? oi : bi;
}

// merge top-2 list (v1,i1,v2,i2) with incoming sorted-2 list (b1,b2).
// Lists are over DISJOINT point sets (butterfly property) -> no dup handling.
__device__ __forceinline__ void mergeTop2_vals(float& v1, int& i1, float& v2,
                                               int& i2, float b1v, int b1i,
                                               float b2v, int b2i) {
  bool c = tgt(b1v, b1i, v1, i1);
  float w1v = c ? b1v : v1; int w1i = c ? b1i : i1;
  float ltv = c ? v1 : b1v; int lti = c ? i1 : b1i;
  float wsv = c ? b2v : v2; int wsi = c ? b2i : i2;
  bool d = tgt(ltv, lti, wsv, wsi);
  v1 = w1v; i1 = w1i;
  v2 = d ? ltv : wsv; i2 = d ? lti : wsi;
}

// DPP-exchange + merge for full 5-field entries (post-barrier 16-slot merge)
template <int CTRL>
__device__ __forceinline__ void mergeTop2_dpp(float& v1, int& i1, float& x1,
                                              float& y1, float& z1, float& v2,
                                              int& i2, float& x2, float& y2,
                                              float& z2) {
  float b1v = dppf<CTRL>(v1); int b1i = dppi<CTRL>(i1);
  float b1x = dppf<CTRL>(x1), b1y = dppf<CTRL>(y1), b1z = dppf<CTRL>(z1);
  float b2v = dppf<CTRL>(v2); int b2i = dppi<CTRL>(i2);
  float b2x = dppf<CTRL>(x2), b2y = dppf<CTRL>(y2), b2z = dppf<CTRL>(z2);
  bool c = tgt(b1v, b1i, v1, i1);
  float w1v = c ? b1v : v1; int w1i = c ? b1i : i1;
  float w1x = c ? b1x : x1, w1y = c ? b1y : y1, w1z = c ? b1z : z1;
  float ltv = c ? v1 : b1v; int lti = c ? i1 : b1i;
  float ltx = c ? x1 : b1x, lty = c ? y1 : b1y, ltz = c ? z1 : b1z;
  float wsv = c ? b2v : v2; int wsi = c ? b2i : i2;
  float wsx = c ? b2x : x2, wsy = c ? b2y : y2, wsz = c ? b2z : z2;
  bool d = tgt(ltv, lti, wsv, wsi);
  v1 = w1v; i1 = w1i; x1 = w1x; y1 = w1y; z1 = w1z;
  v2 = d ? ltv : wsv; i2 = d ? lti : wsi;
  x2 = d ? ltx : wsx; y2 = d ? lty : wsy; z2 = d ? ltz : wsz;
}

// ---------------------------------------------------------------------------
// Spatial counting sort into 16^3 morton cells (one block per batch).
// ---------------------------------------------------------------------------
__device__ __forceinline__ int spread3(int v) {  // 4 bits -> every 3rd bit
  return (v & 1) | ((v & 2) << 2) | ((v & 4) << 4) | ((v & 8) << 6);
}

__global__ __launch_bounds__(1024, 1) void sort_kernel(
    const float* __restrict__ xyz, float* __restrict__ xs,
    float* __restrict__ ys, float* __restrict__ zs, int* __restrict__ io) {
  __shared__ int hist[GCELLS];
  __shared__ int cbase[GCELLS];
  __shared__ int wtot[16];
  __shared__ int woff[16];
  const int b = blockIdx.x;
  const int tid = threadIdx.x;
  const int lane = tid & 63;
  const int wid = tid >> 6;
  const float* xb = xyz + (size_t)b * NN * 3;
  for (int i = tid; i < GCELLS; i += 1024) hist[i] = 0;
  __syncthreads();
  int cell[8];
  float px[8], py[8], pz[8];
#pragma unroll
  for (int k = 0; k < 8; ++k) {
    int j = tid + (k << 10);
    float x = xb[j * 3 + 0], y = xb[j * 3 + 1], z = xb[j * 3 + 2];
    px[k] = x; py[k] = y; pz[k] = z;
    int cx = min(15, max(0, (int)(x * 16.0f)));
    int cy = min(15, max(0, (int)(y * 16.0f)));
    int cz = min(15, max(0, (int)(z * 16.0f)));
    cell[k] = spread3(cx) | (spread3(cy) << 1) | (spread3(cz) << 2);
    atomicAdd(&hist[cell[k]], 1);
  }
  __syncthreads();
  const int i0 = tid * 4;
  int h0 = hist[i0], h1 = hist[i0 + 1], h2 = hist[i0 + 2], h3 = hist[i0 + 3];
  int s4 = h0 + h1 + h2 + h3;
  int v = s4;
#pragma unroll
  for (int d = 1; d < 64; d <<= 1) {
    int o = __shfl_up(v, d);
    if (lane >= d) v += o;
  }
  if (lane == 63) wtot[wid] = v;
  __syncthreads();
  if (tid < 16) {
    int acc = 0;
    for (int w = 0; w < 16; ++w) {
      if (w == tid) woff[tid] = acc;
      acc += wtot[w];
    }
  }
  __syncthreads();
  int eb = woff[wid] + v - s4;
  cbase[i0] = eb;
  cbase[i0 + 1] = eb + h0;
  cbase[i0 + 2] = eb + h0 + h1;
  cbase[i0 + 3] = eb + h0 + h1 + h2;
  __syncthreads();
  for (int i = tid; i < GCELLS; i += 1024) hist[i] = 0;
  __syncthreads();
  const size_t bo = (size_t)b * NN;
#pragma unroll
  for (int k = 0; k < 8; ++k) {
    int pos = cbase[cell[k]] + atomicAdd(&hist[cell[k]], 1);
    xs[bo + pos] = px[k];
    ys[bo + pos] = py[k];
    zs[bo + pos] = pz[k];
    io[bo + pos] = tid + (k << 10);
  }
}

// ---------------------------------------------------------------------------
// Pruned FPS v3: 512 threads/batch (8 waves), 16 sorted pts/thread in regs.
//  - wave-uniform skip: if(__ballot(dirty)) gates update+reduce (clean waves
//    fall straight to the barrier; certified-clean lanes inside a dirty wave
//    run harmlessly: fminf(D,d2)==D bitwise by the certificate).
//  - exact double-pop: reductions carry top-2 by total order (v desc, i asc).
//    After popping c1=i1: every point != i1,i2 has updated value <= v2 and
//    any tie at v2 has index > i2; so iff d2_exact(i2,c1) >= v2, i2 is
//    bitwise the next argmax. No margins involved — exact.
//  - one barrier/round; round-parity LDS entry slots (write current parity
//    pre-barrier, read post-barrier; reuse ordered by the next barrier).
// ---------------------------------------------------------------------------
__global__ __launch_bounds__(512, 1) void fps_kernel(
    const float* __restrict__ xyz, const float* __restrict__ xs,
    const float* __restrict__ ys, const float* __restrict__ zs,
    const int* __restrict__ io, float* __restrict__ newxyz) {
#pragma clang fp contract(off)
  const int b = blockIdx.x;
  const int tid = threadIdx.x;
  const int lane = tid & 63;
  const int wid = tid >> 6;
  const size_t bo = (size_t)b * NN;

  float X[16], Y[16], Z[16], D[16];
  int I[16];
  float gcx, gcy, gcz, gr;
  {
    float mx = 0.f, my = 0.f, mz = 0.f;
#pragma unroll
    for (int k = 0; k < 16; ++k) {
      int s = tid * 16 + k;
      X[k] = xs[bo + s];
      Y[k] = ys[bo + s];
      Z[k] = zs[bo + s];
      I[k] = io[bo + s];
      D[k] = 1e30f;
      mx += X[k]; my += Y[k]; mz += Z[k];
    }
    mx *= 0.0625f; my *= 0.0625f; mz *= 0.0625f;
    float r2m = 0.f;
#pragma unroll
    for (int k = 0; k < 16; ++k)
      r2m = fmaxf(r2m, d2_exact(X[k], Y[k], Z[k], mx, my, mz));
    gcx = mx; gcy = my; gcz = mz;
    gr = __fmul_rn(sqrtf(r2m), 1.0001f) + 1e-6f;  // certified radius UB
  }
  // thread top-2 (value, orig idx, coords)
  float e1v = -1.f, e2v = -1.f;
  int e1i = 0x7fffffff, e2i = 0x7fffffff;
  float e1x = 0.f, e1y = 0.f, e1z = 0.f, e2x = 0.f, e2y = 0.f, e2z = 0.f;
  float T = 3e38f;  // skip threshold: skip center c iff d2(gc,c) >= T
  // wave cached top-2 (v,i)
  float r1v = -1.f, r2v = -1.f;
  int r1i = 0x7fffffff, r2i = 0x7fffffff;

  // [parity][wave][entry][8]: v, i(bits), x, y, z, pad
  __shared__ float ebuf[2][8][2][8];

  const float* xb = xyz + (size_t)b * NN * 3;
  float p1x = xb[0], p1y = xb[1], p1z = xb[2];
  float p2x = p1x, p2y = p1y, p2z = p1z;
  int npop = 1;
  if (tid == 0) {
    newxyz[(size_t)b * NPTS * 3 + 0] = p1x;
    newxyz[(size_t)b * NPTS * 3 + 1] = p1y;
    newxyz[(size_t)b * NPTS * 3 + 2] = p1z;
  }

  int t = 1;
  int rnd = 0;
  while (t < NPTS) {
    const int par = rnd & 1;
    // pruning (per popped center; skip certified => D bitwise unchanged)
    float da = d2_exact(gcx, gcy, gcz, p1x, p1y, p1z);
    bool dirty = da < T;
    if (npop == 2) {
      float db = d2_exact(gcx, gcy, gcz, p2x, p2y, p2z);
      dirty = dirty || (db < T);
    }
    if (__ballot(dirty) != 0ull) {  // wave-uniform -> real s_cbranch skip
      // recompute D and thread top-2 (runs on all lanes; clean lanes no-op)
      float n1v = -1.f, n2v = -1.f;
      int n1i = 0x7fffffff, n2i = 0x7fffffff;
      float n1x = 0.f, n1y = 0.f, n1z = 0.f, n2x = 0.f, n2y = 0.f, n2z = 0.f;
      if (npop == 2) {
#pragma unroll
        for (int k = 0; k < 16; ++k) {
          float d1 = d2_exact(X[k], Y[k], Z[k], p1x, p1y, p1z);
          float d2 = d2_exact(X[k], Y[k], Z[k], p2x, p2y, p2z);
          float nd = fminf(fminf(D[k], d1), d2);
          D[k] = nd;
          bool g1 = tgt(nd, I[k], n1v, n1i);
          bool g2 = tgt(nd, I[k], n2v, n2i);
          float t2v = g1 ? n1v : (g2 ? nd : n2v);
          int t2i = g1 ? n1i : (g2 ? I[k] : n2i);
          float t2x = g1 ? n1x : (g2 ? X[k] : n2x);
          float t2y = g1 ? n1y : (g2 ? Y[k] : n2y);
          float t2z = g1 ? n1z : (g2 ? Z[k] : n2z);
          n1v = g1 ? nd : n1v; n1i = g1 ? I[k] : n1i;
          n1x = g1 ? X[k] : n1x; n1y = g1 ? Y[k] : n1y; n1z = g1 ? Z[k] : n1z;
          n2v = t2v; n2i = t2i; n2x = t2x; n2y = t2y; n2z = t2z;
        }
      } else {
#pragma unroll
        for (int k = 0; k < 16; ++k) {
          float d1 = d2_exact(X[k], Y[k], Z[k], p1x, p1y, p1z);
          float nd = fminf(D[k], d1);
          D[k] = nd;
          bool g1 = tgt(nd, I[k], n1v, n1i);
          bool g2 = tgt(nd, I[k], n2v, n2i);
          float t2v = g1 ? n1v : (g2 ? nd : n2v);
          int t2i = g1 ? n1i : (g2 ? I[k] : n2i);
          float t2x = g1 ? n1x : (g2 ? X[k] : n2x);
          float t2y = g1 ? n1y : (g2 ? Y[k] : n2y);
          float t2z = g1 ? n1z : (g2 ? Z[k] : n2z);
          n1v = g1 ? nd : n1v; n1i = g1 ? I[k] : n1i;
          n1x = g1 ? X[k] : n1x; n1y = g1 ? Y[k] : n1y; n1z = g1 ? Z[k] : n1z;
          n2v = t2v; n2i = t2i; n2x = t2x; n2y = t2y; n2z = t2z;
        }
      }
      e1v = n1v; e1i = n1i; e1x = n1x; e1y = n1y; e1z = n1z;
      e2v = n2v; e2i = n2i; e2x = n2x; e2y = n2y; e2z = n2z;
      // conservative threshold (margins >> fp32 err; same family as R3/R4)
      float s = __fadd_rn(__fmul_rn(sqrtf(e1v), 1.0001f),
                          __fadd_rn(gr, 2e-3f));
      T = __fmul_rn(__fmul_rn(s, s), 1.0001f);
      // in-wave top-2 reduce on (v,i); butterfly over disjoint sets
      float a1v = e1v, a2v = e2v;
      int a1i = e1i, a2i = e2i;
      mergeTop2_vals(a1v, a1i, a2v, a2i, dppf<0xB1>(a1v), dppi<0xB1>(a1i),
                     dppf<0xB1>(a2v), dppi<0xB1>(a2i));
      mergeTop2_vals(a1v, a1i, a2v, a2i, dppf<0x4E>(a1v), dppi<0x4E>(a1i),
                     dppf<0x4E>(a2v), dppi<0x4E>(a2i));
      mergeTop2_vals(a1v, a1i, a2v, a2i, dppf<0x141>(a1v), dppi<0x141>(a1i),
                     dppf<0x141>(a2v), dppi<0x141>(a2i));
      mergeTop2_vals(a1v, a1i, a2v, a2i, dppf<0x140>(a1v), dppi<0x140>(a1i),
                     dppf<0x140>(a2v), dppi<0x140>(a2i));
      mergeTop2_vals(a1v, a1i, a2v, a2i, __shfl_xor(a1v, 16),
                     __shfl_xor(a1i, 16), __shfl_xor(a2v, 16),
                     __shfl_xor(a2i, 16));
      mergeTop2_vals(a1v, a1i, a2v, a2i, __shfl_xor(a1v, 32),
                     __shfl_xor(a1i, 32), __shfl_xor(a2v, 32),
                     __shfl_xor(a2i, 32));
      r1v = a1v; r1i = a1i; r2v = a2v; r2i = a2i;
    }
    // publish current parity slot (every wave, every round — write-side only)
    {
      bool o1a = (e1i == r1i), o1b = (e2i == r1i);
      if (o1a || o1b) {  // unique owner lane of wave entry 1 writes coords
        ebuf[par][wid][0][2] = o1a ? e1x : e2x;
        ebuf[par][wid][0][3] = o1a ? e1y : e2y;
        ebuf[par][wid][0][4] = o1a ? e1z : e2z;
      }
      bool o2a = (e1i == r2i), o2b = (e2i == r2i);
      if (o2a || o2b) {
        ebuf[par][wid][1][2] = o2a ? e1x : e2x;
        ebuf[par][wid][1][3] = o2a ? e1y : e2y;
        ebuf[par][wid][1][4] = o2a ? e1z : e2z;
      }
      if (lane == 0) {
        ebuf[par][wid][0][0] = r1v;
        ebuf[par][wid][0][1] = __int_as_float(r1i);
        ebuf[par][wid][1][0] = r2v;
        ebuf[par][wid][1][1] = __int_as_float(r2i);
      }
    }
    __syncthreads();
    // global top-2 over 16 entries (8 waves x 2); rows see identical sets
    const int w = lane & 7, e = (lane >> 3) & 1;
    const float* ep = &ebuf[par][w][e][0];
    float m1v = ep[0];
    int m1i = __float_as_int(ep[1]);
    float m1x = ep[2], m1y = ep[3], m1z = ep[4];
    float m2v = -1.f; int m2i = 0x7fffffff;
    float m2x = 0.f, m2y = 0.f, m2z = 0.f;
    mergeTop2_dpp<0xB1>(m1v, m1i, m1x, m1y, m1z, m2v, m2i, m2x, m2y, m2z);
    mergeTop2_dpp<0x4E>(m1v, m1i, m1x, m1y, m1z, m2v, m2i, m2x, m2y, m2z);
    mergeTop2_dpp<0x141>(m1v, m1i, m1x, m1y, m1z, m2v, m2i, m2x, m2y, m2z);
    mergeTop2_dpp<0x140>(m1v, m1i, m1x, m1y, m1z, m2v, m2i, m2x, m2y, m2z);
    // pop 1 (always) + exact speculation for pop 2
    bool pop2 = false;
    if (t + 1 < NPTS) {
      float q = d2_exact(m2x, m2y, m2z, m1x, m1y, m1z);
      pop2 = (q >= m2v);
    }
    if (tid == 0) {
      size_t o = ((size_t)b * NPTS + t) * 3;
      newxyz[o + 0] = m1x; newxyz[o + 1] = m1y; newxyz[o + 2] = m1z;
      if (pop2) {
        newxyz[o + 3] = m2x; newxyz[o + 4] = m2y; newxyz[o + 5] = m2z;
      }
    }
    p1x = m1x; p1y = m1y; p1z = m1z;
    p2x = m2x; p2y = m2y; p2z = m2z;
    npop = pop2 ? 2 : 1;
    t += npop;
    ++rnd;
  }
}

// ---------------------------------------------------------------------------
// Fallback FPS (no workspace): R2's 1024-thread register kernel.
// ---------------------------------------------------------------------------
__global__ __launch_bounds__(1024, 1) void fps_nosort_kernel(
    const float* __restrict__ xyz, float* __restrict__ newxyz) {
#pragma clang fp contract(off)
  const int b = blockIdx.x;
  const int tid = threadIdx.x;
  const int lane = tid & 63;
  const int wid = tid >> 6;
  const float* xb = xyz + (size_t)b * NN * 3;
  v2f x2[4], y2[4], z2[4], dd[4];
#pragma unroll
  for (int p = 0; p < 4; ++p) {
    int j0 = tid + ((2 * p) << 10);
    int j1 = tid + ((2 * p + 1) << 10);
    x2[p].x = xb[j0 * 3 + 0]; x2[p].y = xb[j1 * 3 + 0];
    y2[p].x = xb[j0 * 3 + 1]; y2[p].y = xb[j1 * 3 + 1];
    z2[p].x = xb[j0 * 3 + 2]; z2[p].y = xb[j1 * 3 + 2];
    dd[p].x = 1e10f; dd[p].y = 1e10f;
  }
  __shared__ float vbuf[2][16];
  __shared__ int ibuf[2][16];
  __shared__ float cbuf[2][16][3];
  float cx = xb[0], cy = xb[1], cz = xb[2];
  if (tid == 0) {
    newxyz[(size_t)b * NPTS * 3 + 0] = cx;
    newxyz[(size_t)b * NPTS * 3 + 1] = cy;
    newxyz[(size_t)b * NPTS * 3 + 2] = cz;
  }
  for (int t = 1; t < NPTS; ++t) {
    const int par = t & 1;
    float bv = -1.0f; int bi = 0;
    float bwx = 0.f, bwy = 0.f, bwz = 0.f;
#pragma unroll
    for (int p = 0; p < 4; ++p) {
      v2f dx = x2[p] - (v2f){cx, cx};
      v2f dy = y2[p] - (v2f){cy, cy};
      v2f dz = z2[p] - (v2f){cz, cz};
      v2f s = dx * dx + dy * dy + dz * dz;
      v2f nd;
      nd.x = fminf(dd[p].x, s.x);
      nd.y = fminf(dd[p].y, s.y);
      dd[p] = nd;
      { bool c = nd.x > bv;
        bv = c ? nd.x : bv; bi = c ? (tid + ((2 * p) << 10)) : bi;
        bwx = c ? x2[p].x : bwx; bwy = c ? y2[p].x : bwy; bwz = c ? z2[p].x : bwz; }
      { bool c = nd.y > bv;
        bv = c ? nd.y : bv; bi = c ? (tid + ((2 * p + 1) << 10)) : bi;
        bwx = c ? x2[p].y : bwx; bwy = c ? y2[p].y : bwy; bwz = c ? z2[p].y : bwz; }
    }
    red_pair(bv, bi, dppf<0xB1>(bv), dppi<0xB1>(bi));
    red_pair(bv, bi, dppf<0x4E>(bv), dppi<0x4E>(bi));
    red_pair(bv, bi, dppf<0x141>(bv), dppi<0x141>(bi));
    red_pair(bv, bi, dppf<0x140>(bv), dppi<0x140>(bi));
    red_pair(bv, bi, __shfl_xor(bv, 16), __shfl_xor(bi, 16));
    red_pair(bv, bi, __shfl_xor(bv, 32), __shfl_xor(bi, 32));
    if (tid == (bi & 1023)) {
      vbuf[par][wid] = bv; ibuf[par][wid] = bi;
      cbuf[par][wid][0] = bwx; cbuf[par][wid][1] = bwy; cbuf[par][wid][2] = bwz;
    }
    __syncthreads();
    float v2w = vbuf[par][lane & 15];
    int i2w = ibuf[par][lane & 15];
    red_pair(v2w, i2w, dppf<0xB1>(v2w), dppi<0xB1>(i2w));
    red_pair(v2w, i2w, dppf<0x4E>(v2w), dppi<0x4E>(i2w));
    red_pair(v2w, i2w, dppf<0x141>(v2w), dppi<0x141>(i2w));
    red_pair(v2w, i2w, dppf<0x140>(v2w), dppi<0x140>(i2w));
    const int slot = (i2w & 1023) >> 6;
    cx = cbuf[par][slot][0]; cy = cbuf[par][slot][1]; cz = cbuf[par][slot][2];
    if (tid == (i2w & 1023)) {
      size_t o = ((size_t)b * NPTS + t) * 3;
      newxyz[o + 0] = cx; newxyz[o + 1] = cy; newxyz[o + 2] = cz;
    }
  }
}

// ---------------------------------------------------------------------------
// Ball query: one wave per center; ballot scan in index order -> first 32 hits.
// ---------------------------------------------------------------------------
__global__ __launch_bounds__(256) void ballq_kernel(
    const float* __restrict__ xyz, const float* __restrict__ newxyz,
    int* __restrict__ bidx) {
  const int cid = blockIdx.x * 4 + (threadIdx.x >> 6);
  const int lane = threadIdx.x & 63;
  const int b = cid >> 11;
  const float* xb = xyz + (size_t)b * NN * 3;
  const float cx = newxyz[(size_t)cid * 3 + 0];
  const float cy = newxyz[(size_t)cid * 3 + 1];
  const float cz = newxyz[(size_t)cid * 3 + 2];
  int* ob = bidx + (size_t)cid * NSAMP;
  int total = 0;
  int first = -1;
  for (int c0 = 0; c0 < NN; c0 += 64) {
    int j = c0 + lane;
    float xx = xb[j * 3 + 0], yy = xb[j * 3 + 1], zz = xb[j * 3 + 2];
    float d2 = d2_exact(cx, cy, cz, xx, yy, zz);
    bool in = d2 <= 0.04f;
    unsigned long long m = __ballot(in);
    if (first < 0 && m) first = c0 + __builtin_ctzll(m);
    int pos = total + __popcll(m & ((1ull << lane) - 1ull));
    if (in && pos < NSAMP) ob[pos] = j;
    total += __popcll(m);
    if (total >= NSAMP) break;
  }
  if (total < NSAMP && lane < NSAMP - total) ob[total + lane] = first;
}

// ---------------------------------------------------------------------------
__global__ void tw_kernel(const float* __restrict__ W1, const float* __restrict__ W2,
                          const float* __restrict__ Wsa, float* __restrict__ w1t,
                          float* __restrict__ w2t, float* __restrict__ wsat) {
  int i = blockIdx.x * blockDim.x + threadIdx.x;
  if (i < CIN * NH1) w1t[i] = W1[(i % NH1) * CIN + (i / NH1)];
  if (i < NH1 * NH2) w2t[i] = W2[(i % NH2) * NH1 + (i / NH2)];
  if (i < NH2 * NOUTC) wsat[i] = Wsa[(i % NOUTC) * NH2 + (i / NOUTC)];
}

__global__ void tfeat_kernel(const float* __restrict__ feat, float* __restrict__ featT) {
  __shared__ float tile[32][33];
  const int b = blockIdx.z;
  const int n0 = blockIdx.x * 32, c0 = blockIdx.y * 32;
  const int tx = threadIdx.x, ty = threadIdx.y;
#pragma unroll
  for (int r = 0; r < 4; ++r)
    tile[ty + r * 8][tx] = feat[((size_t)b * NC + c0 + ty + r * 8) * NN + n0 + tx];
  __syncthreads();
#pragma unroll
  for (int r = 0; r < 4; ++r)
    featT[((size_t)b * NN + n0 + ty + r * 8) * NC + c0 + tx] = tile[tx][ty + r * 8];
}

// ---------------------------------------------------------------------------
// Fused gather + MLP(64,128) + maxpool + final linear, one block per center.
// ---------------------------------------------------------------------------
#define HS 36
__global__ __launch_bounds__(256) void mlp_kernel(
    const float* __restrict__ xyz, const float* __restrict__ fsrc,
    const float* __restrict__ newxyz, const int* __restrict__ bidx,
    const float* __restrict__ w1t, const float* __restrict__ b1,
    const float* __restrict__ w2t, const float* __restrict__ b2,
    const float* __restrict__ wsat, const float* __restrict__ bsa,
    float* __restrict__ out1, int useT) {
  __shared__ float h[CIN * HS];
  __shared__ float h1[NH1 * HS];
  __shared__ float pl[256];
  __shared__ float pooled[NH2];
  __shared__ int sidx[NSAMP];
  __shared__ float sc[3];
  const int cid = blockIdx.x;
  const int b = cid >> 11;
  const int s = cid & 2047;
  const int tid = threadIdx.x;
  if (tid < NSAMP) sidx[tid] = bidx[(size_t)cid * NSAMP + tid];
  if (tid < 3) sc[tid] = newxyz[(size_t)cid * 3 + tid];
  __syncthreads();
  {
    const int ss = tid >> 3, q = tid & 7;
    const int j = sidx[ss];
    if (useT) {
      const float4* fr = (const float4*)(fsrc + ((size_t)b * NN + j) * NC + q * 16);
#pragma unroll
      for (int u = 0; u < 4; ++u) {
        float4 v = fr[u];
        int c = 3 + q * 16 + u * 4;
        h[(c + 0) * HS + ss] = v.x;
        h[(c + 1) * HS + ss] = v.y;
        h[(c + 2) * HS + ss] = v.z;
        h[(c + 3) * HS + ss] = v.w;
      }
    } else {
      for (int u = 0; u < 16; ++u) {
        int c = q * 16 + u;
        h[(3 + c) * HS + ss] = fsrc[((size_t)b * NC + c) * NN + j];
      }
    }
    if (q == 0) {
      const float* pr = xyz + ((size_t)b * NN + j) * 3;
      h[0 * HS + ss] = pr[0] - sc[0];
      h[1 * HS + ss] = pr[1] - sc[1];
      h[2 * HS + ss] = pr[2] - sc[2];
    }
  }
  __syncthreads();
  {
    const int o = tid & 63, sg = tid >> 6;
    float acc[8];
    const float bb = b1[o];
#pragma unroll
    for (int i = 0; i < 8; ++i) acc[i] = bb;
    const float4* hb = (const float4*)&h[sg * 8];
    for (int k = 0; k < CIN; ++k) {
      float w = w1t[k * NH1 + o];
      float4 a = hb[k * (HS / 4) + 0];
      float4 c = hb[k * (HS / 4) + 1];
      acc[0] = fmaf(w, a.x, acc[0]); acc[1] = fmaf(w, a.y, acc[1]);
      acc[2] = fmaf(w, a.z, acc[2]); acc[3] = fmaf(w, a.w, acc[3]);
      acc[4] = fmaf(w, c.x, acc[4]); acc[5] = fmaf(w, c.y, acc[5]);
      acc[6] = fmaf(w, c.z, acc[6]); acc[7] = fmaf(w, c.w, acc[7]);
    }
#pragma unroll
    for (int i = 0; i < 8; ++i) h1[o * HS + sg * 8 + i] = fmaxf(acc[i], 0.0f);
  }
  __syncthreads();
  {
    const int o = tid & 127, sg = tid >> 7;
    float acc[16];
    const float bb = b2[o];
#pragma unroll
    for (int i = 0; i < 16; ++i) acc[i] = bb;
    const float4* hb = (const float4*)&h1[sg * 16];
    for (int k = 0; k < NH1; ++k) {
      float w = w2t[k * NH2 + o];
#pragma unroll
      for (int u = 0; u < 4; ++u) {
        float4 a = hb[k * (HS / 4) + u];
        acc[u * 4 + 0] = fmaf(w, a.x, acc[u * 4 + 0]);
        acc[u * 4 + 1] = fmaf(w, a.y, acc[u * 4 + 1]);
        acc[u * 4 + 2] = fmaf(w, a.z, acc[u * 4 + 2]);
        acc[u * 4 + 3] = fmaf(w, a.w, acc[u * 4 + 3]);
      }
    }
    float pm = acc[0];
#pragma unroll
    for (int i = 1; i < 16; ++i) pm = fmaxf(pm, acc[i]);
    pl[sg * 128 + o] = pm;
  }
  __syncthreads();
  if (tid < NH2) pooled[tid] = fmaxf(fmaxf(pl[tid], pl[128 + tid]), 0.0f);
  __syncthreads();
  if (tid < NOUTC) {
    float acc = bsa[tid];
    for (int k = 0; k < NH2; ++k) acc = fmaf(pooled[k], wsat[k * NOUTC + tid], acc);
    out1[((size_t)b * NOUTC + tid) * NPTS + s] = acc;
  }
}

extern "C" void kernel_launch(void* const* d_in, const int* in_sizes, int n_in,
                              void* d_out, int out_size, void* d_ws, size_t ws_size,
                              hipStream_t stream) {
  const float* xyz = (const float*)d_in[0];
  const float* feat = (const float*)d_in[1];
  const float* W1 = (const float*)d_in[2];
  const float* b1 = (const float*)d_in[3];
  const float* W2 = (const float*)d_in[4];
  const float* b2 = (const float*)d_in[5];
  const float* Wsa = (const float*)d_in[6];
  const float* bsa = (const float*)d_in[7];
  float* out = (float*)d_out;
  float* newxyz = out;                       // (B, NPTS, 3)
  float* out1 = out + (size_t)NB * NPTS * 3; // (B, OUT, NPTS)

  const size_t sort_f = (size_t)NB * NN * 4;  // xs, ys, zs, io
  const size_t small_f = (size_t)CIN * NH1 + NH1 * NH2 + NH2 * NOUTC +
                         (size_t)NB * NPTS * NSAMP;
  const size_t featT_f = (size_t)NB * NN * NC;

  float* ws = (float*)d_ws;
  bool useSort = ws_size >= (sort_f + small_f) * 4;
  bool useT = ws_size >= (sort_f + small_f + featT_f) * 4;

  float* xs = ws;
  float* ysr = xs + (size_t)NB * NN;
  float* zsr = ysr + (size_t)NB * NN;
  int* iosr = (int*)(zsr + (size_t)NB * NN);
  float* base2 = useSort ? (ws + sort_f) : ws;
  float* w1t = base2;
  float* w2t = w1t + CIN * NH1;
  float* wsat = w2t + NH1 * NH2;
  int* bidx = (int*)(wsat + NH2 * NOUTC);
  float* featT = (float*)(bidx + (size_t)NB * NPTS * NSAMP);

  tw_kernel<<<64, 256, 0, stream>>>(W1, W2, Wsa, w1t, w2t, wsat);
  if (useT)
    tfeat_kernel<<<dim3(NN / 32, NC / 32, NB), dim3(32, 8), 0, stream>>>(feat, featT);
  if (useSort) {
    sort_kernel<<<NB, 1024, 0, stream>>>(xyz, xs, ysr, zsr, iosr);
    fps_kernel<<<NB, 512, 0, stream>>>(xyz, xs, ysr, zsr, iosr, newxyz);
  } else {
    fps_nosort_kernel<<<NB, 1024, 0, stream>>>(xyz, newxyz);
  }
  ballq_kernel<<<NB * NPTS / 4, 256, 0, stream>>>(xyz, newxyz, bidx);
  mlp_kernel<<<NB * NPTS, 256, 0, stream>>>(xyz, useT ? featT : feat, newxyz, bidx,
                                            w1t, b1, w2t, b2, wsat, bsa, out1,
                                            (int)useT);
}

// Round 6
// 3709.201 us; speedup vs baseline: 1.1236x; 1.0532x over previous
//
#include <hip/hip_runtime.h>
#include <cstdint>
#include <cstddef>

#define NB 4
#define NN 8192
#define NPTS 2048
#define NSAMP 32
#define NC 128
#define CIN 131      // 3 + NC
#define NH1 64
#define NH2 128
#define NOUTC 128
#define GCELLS 4096  // 16x16x16 morton grid

typedef float v2f __attribute__((ext_vector_type(2)));

// Exact (numpy-order, contraction-free) squared distance:
// ((dx*dx + dy*dy) + dz*dz), round-to-nearest each op, no FMA.
__device__ __forceinline__ float d2_exact(float ax, float ay, float az,
                                          float bx, float by, float bz) {
  float dx = ax - bx, dy = ay - by, dz = az - bz;
  return __fadd_rn(__fadd_rn(__fmul_rn(dx, dx), __fmul_rn(dy, dy)),
                   __fmul_rn(dz, dz));
}

// ---- DPP cross-lane (VALU, no LDS). 0xB1=xor1 0x4E=xor2 0x141=xor7(row half
// mirror) 0x140=xor15(row mirror) — {1,2,7,15} spans 4 bits -> 16-lane allreduce.
#if __has_builtin(__builtin_amdgcn_mov_dpp)
template <int CTRL>
__device__ __forceinline__ float dppf(float v) {
  return __int_as_float(
      __builtin_amdgcn_mov_dpp(__float_as_int(v), CTRL, 0xF, 0xF, true));
}
template <int CTRL>
__device__ __forceinline__ int dppi(int v) {
  return __builtin_amdgcn_mov_dpp(v, CTRL, 0xF, 0xF, true);
}
#else
template <int CTRL>
__device__ __forceinline__ float dppf(float v) {
  const int m = (CTRL == 0xB1) ? 1 : (CTRL == 0x4E) ? 2 : (CTRL == 0x141) ? 7 : 15;
  return __shfl_xor(v, m);
}
template <int CTRL>
__device__ __forceinline__ int dppi(int v) {
  const int m = (CTRL == 0xB1) ? 1 : (CTRL == 0x4E) ? 2 : (CTRL == 0x141) ? 7 : 15;
  return __shfl_xor(v, m);
}
#endif

// total order: (value desc, index asc). distinct points => strict.
__device__ __forceinline__ bool tgt(float av, int ai, float bv, int bi) {
  return (av > bv) || (av == bv && ai < bi);
}

// argmax combine for (v,i) pairs
__device__ __forceinline__ void red_pair(float& bv, int& bi, float ov, int oi) {
  bool t = tgt(ov, oi, bv, bi);
  bv = t ? ov : bv;
  bi = t ? oi : bi;
}
// same comparator, carrying coords through row-local DPP
template <int CTRL>
__device__ __forceinline__ void red5(float& v, int& i, float& x, float& y,
                                     float& z) {
  float ov = dppf<CTRL>(v);
  int oi = dppi<CTRL>(i);
  float ox = dppf<CTRL>(x), oy = dppf<CTRL>(y), oz = dppf<CTRL>(z);
  bool t = tgt(ov, oi, v, i);
  v = t ? ov : v; i = t ? oi : i;
  x = t ? ox : x; y = t ? oy : y; z = t ? oz : z;
}

// ---------------------------------------------------------------------------
// Spatial counting sort into 16^3 morton cells (one block per batch).
// Order within a cell is nondeterministic (LDS atomics) — harmless: FPS
// selection is order-independent (total order on (value, orig_idx)).
// ---------------------------------------------------------------------------
__device__ __forceinline__ int spread3(int v) {  // 4 bits -> every 3rd bit
  return (v & 1) | ((v & 2) << 2) | ((v & 4) << 4) | ((v & 8) << 6);
}

__global__ __launch_bounds__(1024, 1) void sort_kernel(
    const float* __restrict__ xyz, float* __restrict__ xs,
    float* __restrict__ ys, float* __restrict__ zs, int* __restrict__ io) {
  __shared__ int hist[GCELLS];
  __shared__ int cbase[GCELLS];
  __shared__ int wtot[16];
  __shared__ int woff[16];
  const int b = blockIdx.x;
  const int tid = threadIdx.x;
  const int lane = tid & 63;
  const int wid = tid >> 6;
  const float* xb = xyz + (size_t)b * NN * 3;
  for (int i = tid; i < GCELLS; i += 1024) hist[i] = 0;
  __syncthreads();
  int cell[8];
  float px[8], py[8], pz[8];
#pragma unroll
  for (int k = 0; k < 8; ++k) {
    int j = tid + (k << 10);
    float x = xb[j * 3 + 0], y = xb[j * 3 + 1], z = xb[j * 3 + 2];
    px[k] = x; py[k] = y; pz[k] = z;
    int cx = min(15, max(0, (int)(x * 16.0f)));
    int cy = min(15, max(0, (int)(y * 16.0f)));
    int cz = min(15, max(0, (int)(z * 16.0f)));
    cell[k] = spread3(cx) | (spread3(cy) << 1) | (spread3(cz) << 2);
    atomicAdd(&hist[cell[k]], 1);
  }
  __syncthreads();
  const int i0 = tid * 4;
  int h0 = hist[i0], h1 = hist[i0 + 1], h2 = hist[i0 + 2], h3 = hist[i0 + 3];
  int s4 = h0 + h1 + h2 + h3;
  int v = s4;
#pragma unroll
  for (int d = 1; d < 64; d <<= 1) {
    int o = __shfl_up(v, d);
    if (lane >= d) v += o;
  }
  if (lane == 63) wtot[wid] = v;
  __syncthreads();
  if (tid < 16) {
    int acc = 0;
    for (int w = 0; w < 16; ++w) {
      if (w == tid) woff[tid] = acc;
      acc += wtot[w];
    }
  }
  __syncthreads();
  int eb = woff[wid] + v - s4;
  cbase[i0] = eb;
  cbase[i0 + 1] = eb + h0;
  cbase[i0 + 2] = eb + h0 + h1;
  cbase[i0 + 3] = eb + h0 + h1 + h2;
  __syncthreads();
  for (int i = tid; i < GCELLS; i += 1024) hist[i] = 0;
  __syncthreads();
  const size_t bo = (size_t)b * NN;
#pragma unroll
  for (int k = 0; k < 8; ++k) {
    int pos = cbase[cell[k]] + atomicAdd(&hist[cell[k]], 1);
    xs[bo + pos] = px[k];
    ys[bo + pos] = py[k];
    zs[bo + pos] = pz[k];
    io[bo + pos] = tid + (k << 10);
  }
}

// ---------------------------------------------------------------------------
// Pruned FPS v4: 1024 threads/batch, one morton group of 8 pts per thread,
// register-resident. The WHOLE update (per-lane work + wave reduce + cache
// refresh) sits inside a wave-uniform `if (__ballot(dirty))` — SGPR condition
// -> real s_cbranch skip for clean waves (R4's per-lane `if` was if-converted,
// which is why pruning never showed up in time). Inside a dirty wave all
// lanes run: certified-clean lanes recompute bitwise-identical values
// (fminf(D,d2)==D by the triangle-inequality certificate, margins 2e-3 >>
// fp32 err). Wave candidate cache stays exact: any wave containing a changed
// point is dirty by construction (the popped point's own group always is).
// One barrier/step; parity LDS slots; 4-level DPP merge carrying (v,i,x,y,z).
// Comparator everywhere: (dist desc, orig idx asc) == np.argmax semantics.
// ---------------------------------------------------------------------------
__global__ __launch_bounds__(1024, 1) void fps_kernel(
    const float* __restrict__ xyz, const float* __restrict__ xs,
    const float* __restrict__ ys, const float* __restrict__ zs,
    const int* __restrict__ io, float* __restrict__ newxyz) {
#pragma clang fp contract(off)
  const int b = blockIdx.x;
  const int tid = threadIdx.x;
  const int lane = tid & 63;
  const int wid = tid >> 6;
  const size_t bo = (size_t)b * NN;

  float X[8], Y[8], Z[8], D[8];
  int I[8];
  float gcx, gcy, gcz, gr;
  {
    float mx = 0.f, my = 0.f, mz = 0.f;
#pragma unroll
    for (int k = 0; k < 8; ++k) {
      int s = tid * 8 + k;
      X[k] = xs[bo + s];
      Y[k] = ys[bo + s];
      Z[k] = zs[bo + s];
      I[k] = io[bo + s];
      D[k] = 1e30f;
      mx += X[k]; my += Y[k]; mz += Z[k];
    }
    mx *= 0.125f; my *= 0.125f; mz *= 0.125f;
    float r2m = 0.f;
#pragma unroll
    for (int k = 0; k < 8; ++k)
      r2m = fmaxf(r2m, d2_exact(X[k], Y[k], Z[k], mx, my, mz));
    gcx = mx; gcy = my; gcz = mz;
    gr = __fmul_rn(sqrtf(r2m), 1.0001f) + 1e-6f;  // certified radius UB
  }
  float gv = -1.0f;                         // thread candidate (group max)
  int gidx = 0x7fffffff;
  float gx = 0.f, gy = 0.f, gz = 0.f;
  float T = 3e38f;                          // skip iff d2(gc,c) >= T
  float cv = -1.0f; int ci = 0x7fffffff;    // wave cache
  float ccx = 0.f, ccy = 0.f, ccz = 0.f;

  __shared__ float sv[2][16];
  __shared__ int si[2][16];
  __shared__ float sxx[2][16], syy[2][16], szz[2][16];

  const float* xb = xyz + (size_t)b * NN * 3;
  float cx = xb[0], cy = xb[1], cz = xb[2];
  if (tid == 0) {
    newxyz[(size_t)b * NPTS * 3 + 0] = cx;
    newxyz[(size_t)b * NPTS * 3 + 1] = cy;
    newxyz[(size_t)b * NPTS * 3 + 2] = cz;
  }

  for (int t = 1; t < NPTS; ++t) {
    const int par = t & 1;
    const float d2c = d2_exact(gcx, gcy, gcz, cx, cy, cz);
    const bool dirty = d2c < T;
    if (__ballot(dirty) != 0ull) {  // wave-uniform -> real skip for clean waves
      float nv = -1.f; int ni = 0x7fffffff;
      float nx = 0.f, ny = 0.f, nz = 0.f;
#pragma unroll
      for (int k = 0; k < 8; ++k) {
        float dd = d2_exact(X[k], Y[k], Z[k], cx, cy, cz);
        float nd = fminf(D[k], dd);
        D[k] = nd;
        bool c = tgt(nd, I[k], nv, ni);
        nv = c ? nd : nv; ni = c ? I[k] : ni;
        nx = c ? X[k] : nx; ny = c ? Y[k] : ny; nz = c ? Z[k] : nz;
      }
      gv = nv; gidx = ni; gx = nx; gy = ny; gz = nz;
      // conservative skip threshold (same certified family as R3-R5)
      float s = __fadd_rn(__fmul_rn(sqrtf(gv), 1.0001f),
                          __fadd_rn(gr, 2e-3f));
      T = __fmul_rn(__fmul_rn(s, s), 1.0001f);
      // wave top-1 allreduce on (v, orig idx)
      float rv = gv; int ri = gidx;
      red_pair(rv, ri, dppf<0xB1>(rv), dppi<0xB1>(ri));
      red_pair(rv, ri, dppf<0x4E>(rv), dppi<0x4E>(ri));
      red_pair(rv, ri, dppf<0x141>(rv), dppi<0x141>(ri));
      red_pair(rv, ri, dppf<0x140>(rv), dppi<0x140>(ri));
      red_pair(rv, ri, __shfl_xor(rv, 16), __shfl_xor(ri, 16));
      red_pair(rv, ri, __shfl_xor(rv, 32), __shfl_xor(ri, 32));
      unsigned long long m = __ballot(gidx == ri);  // exactly one lane
      int owner = (int)__builtin_ctzll(m);
      cv = rv; ci = ri;
      ccx = __shfl(gx, owner);
      ccy = __shfl(gy, owner);
      ccz = __shfl(gz, owner);
    }
    if (lane == 0) {  // publish wave cache (16 consecutive banks, no conflict)
      sv[par][wid] = cv; si[par][wid] = ci;
      sxx[par][wid] = ccx; syy[par][wid] = ccy; szz[par][wid] = ccz;
    }
    __syncthreads();
    // 16-slot merge, all threads (row-local DPP, no second LDS hop)
    const int sl = lane & 15;
    float v = sv[par][sl];
    int i = si[par][sl];
    float xx = sxx[par][sl], yy = syy[par][sl], zz = szz[par][sl];
    red5<0xB1>(v, i, xx, yy, zz);
    red5<0x4E>(v, i, xx, yy, zz);
    red5<0x141>(v, i, xx, yy, zz);
    red5<0x140>(v, i, xx, yy, zz);
    cx = xx; cy = yy; cz = zz;
    if (gidx == i) {  // unique global owner writes the center
      size_t o = ((size_t)b * NPTS + t) * 3;
      newxyz[o + 0] = xx; newxyz[o + 1] = yy; newxyz[o + 2] = zz;
    }
    // one barrier/step: parity slots; reuse at t+2 ordered by t+1's barrier
  }
}

// ---------------------------------------------------------------------------
// Fallback FPS (no workspace): R2's 1024-thread register kernel.
// ---------------------------------------------------------------------------
__global__ __launch_bounds__(1024, 1) void fps_nosort_kernel(
    const float* __restrict__ xyz, float* __restrict__ newxyz) {
#pragma clang fp contract(off)
  const int b = blockIdx.x;
  const int tid = threadIdx.x;
  const int lane = tid & 63;
  const int wid = tid >> 6;
  const float* xb = xyz + (size_t)b * NN * 3;
  v2f x2[4], y2[4], z2[4], dd[4];
#pragma unroll
  for (int p = 0; p < 4; ++p) {
    int j0 = tid + ((2 * p) << 10);
    int j1 = tid + ((2 * p + 1) << 10);
    x2[p].x = xb[j0 * 3 + 0]; x2[p].y = xb[j1 * 3 + 0];
    y2[p].x = xb[j0 * 3 + 1]; y2[p].y = xb[j1 * 3 + 1];
    z2[p].x = xb[j0 * 3 + 2]; z2[p].y = xb[j1 * 3 + 2];
    dd[p].x = 1e10f; dd[p].y = 1e10f;
  }
  __shared__ float vbuf[2][16];
  __shared__ int ibuf[2][16];
  __shared__ float cbuf[2][16][3];
  float cx = xb[0], cy = xb[1], cz = xb[2];
  if (tid == 0) {
    newxyz[(size_t)b * NPTS * 3 + 0] = cx;
    newxyz[(size_t)b * NPTS * 3 + 1] = cy;
    newxyz[(size_t)b * NPTS * 3 + 2] = cz;
  }
  for (int t = 1; t < NPTS; ++t) {
    const int par = t & 1;
    float bv = -1.0f; int bi = 0;
    float bwx = 0.f, bwy = 0.f, bwz = 0.f;
#pragma unroll
    for (int p = 0; p < 4; ++p) {
      v2f dx = x2[p] - (v2f){cx, cx};
      v2f dy = y2[p] - (v2f){cy, cy};
      v2f dz = z2[p] - (v2f){cz, cz};
      v2f s = dx * dx + dy * dy + dz * dz;
      v2f nd;
      nd.x = fminf(dd[p].x, s.x);
      nd.y = fminf(dd[p].y, s.y);
      dd[p] = nd;
      { bool c = nd.x > bv;
        bv = c ? nd.x : bv; bi = c ? (tid + ((2 * p) << 10)) : bi;
        bwx = c ? x2[p].x : bwx; bwy = c ? y2[p].x : bwy; bwz = c ? z2[p].x : bwz; }
      { bool c = nd.y > bv;
        bv = c ? nd.y : bv; bi = c ? (tid + ((2 * p + 1) << 10)) : bi;
        bwx = c ? x2[p].y : bwx; bwy = c ? y2[p].y : bwy; bwz = c ? z2[p].y : bwz; }
    }
    red_pair(bv, bi, dppf<0xB1>(bv), dppi<0xB1>(bi));
    red_pair(bv, bi, dppf<0x4E>(bv), dppi<0x4E>(bi));
    red_pair(bv, bi, dppf<0x141>(bv), dppi<0x141>(bi));
    red_pair(bv, bi, dppf<0x140>(bv), dppi<0x140>(bi));
    red_pair(bv, bi, __shfl_xor(bv, 16), __shfl_xor(bi, 16));
    red_pair(bv, bi, __shfl_xor(bv, 32), __shfl_xor(bi, 32));
    if (tid == (bi & 1023)) {
      vbuf[par][wid] = bv; ibuf[par][wid] = bi;
      cbuf[par][wid][0] = bwx; cbuf[par][wid][1] = bwy; cbuf[par][wid][2] = bwz;
    }
    __syncthreads();
    float v2w = vbuf[par][lane & 15];
    int i2w = ibuf[par][lane & 15];
    red_pair(v2w, i2w, dppf<0xB1>(v2w), dppi<0xB1>(i2w));
    red_pair(v2w, i2w, dppf<0x4E>(v2w), dppi<0x4E>(i2w));
    red_pair(v2w, i2w, dppf<0x141>(v2w), dppi<0x141>(i2w));
    red_pair(v2w, i2w, dppf<0x140>(v2w), dppi<0x140>(i2w));
    const int slot = (i2w & 1023) >> 6;
    cx = cbuf[par][slot][0]; cy = cbuf[par][slot][1]; cz = cbuf[par][slot][2];
    if (tid == (i2w & 1023)) {
      size_t o = ((size_t)b * NPTS + t) * 3;
      newxyz[o + 0] = cx; newxyz[o + 1] = cy; newxyz[o + 2] = cz;
    }
  }
}

// ---------------------------------------------------------------------------
// Ball query: one wave per center; ballot scan in index order -> first 32 hits.
// ---------------------------------------------------------------------------
__global__ __launch_bounds__(256) void ballq_kernel(
    const float* __restrict__ xyz, const float* __restrict__ newxyz,
    int* __restrict__ bidx) {
  const int cid = blockIdx.x * 4 + (threadIdx.x >> 6);
  const int lane = threadIdx.x & 63;
  const int b = cid >> 11;
  const float* xb = xyz + (size_t)b * NN * 3;
  const float cx = newxyz[(size_t)cid * 3 + 0];
  const float cy = newxyz[(size_t)cid * 3 + 1];
  const float cz = newxyz[(size_t)cid * 3 + 2];
  int* ob = bidx + (size_t)cid * NSAMP;
  int total = 0;
  int first = -1;
  for (int c0 = 0; c0 < NN; c0 += 64) {
    int j = c0 + lane;
    float xx = xb[j * 3 + 0], yy = xb[j * 3 + 1], zz = xb[j * 3 + 2];
    float d2 = d2_exact(cx, cy, cz, xx, yy, zz);
    bool in = d2 <= 0.04f;
    unsigned long long m = __ballot(in);
    if (first < 0 && m) first = c0 + __builtin_ctzll(m);
    int pos = total + __popcll(m & ((1ull << lane) - 1ull));
    if (in && pos < NSAMP) ob[pos] = j;
    total += __popcll(m);
    if (total >= NSAMP) break;
  }
  if (total < NSAMP && lane < NSAMP - total) ob[total + lane] = first;
}

// ---------------------------------------------------------------------------
__global__ void tw_kernel(const float* __restrict__ W1, const float* __restrict__ W2,
                          const float* __restrict__ Wsa, float* __restrict__ w1t,
                          float* __restrict__ w2t, float* __restrict__ wsat) {
  int i = blockIdx.x * blockDim.x + threadIdx.x;
  if (i < CIN * NH1) w1t[i] = W1[(i % NH1) * CIN + (i / NH1)];
  if (i < NH1 * NH2) w2t[i] = W2[(i % NH2) * NH1 + (i / NH2)];
  if (i < NH2 * NOUTC) wsat[i] = Wsa[(i % NOUTC) * NH2 + (i / NOUTC)];
}

__global__ void tfeat_kernel(const float* __restrict__ feat, float* __restrict__ featT) {
  __shared__ float tile[32][33];
  const int b = blockIdx.z;
  const int n0 = blockIdx.x * 32, c0 = blockIdx.y * 32;
  const int tx = threadIdx.x, ty = threadIdx.y;
#pragma unroll
  for (int r = 0; r < 4; ++r)
    tile[ty + r * 8][tx] = feat[((size_t)b * NC + c0 + ty + r * 8) * NN + n0 + tx];
  __syncthreads();
#pragma unroll
  for (int r = 0; r < 4; ++r)
    featT[((size_t)b * NN + n0 + ty + r * 8) * NC + c0 + tx] = tile[tx][ty + r * 8];
}

// ---------------------------------------------------------------------------
// Fused gather + MLP(64,128) + maxpool + final linear, one block per center.
// ---------------------------------------------------------------------------
#define HS 36
__global__ __launch_bounds__(256) void mlp_kernel(
    const float* __restrict__ xyz, const float* __restrict__ fsrc,
    const float* __restrict__ newxyz, const int* __restrict__ bidx,
    const float* __restrict__ w1t, const float* __restrict__ b1,
    const float* __restrict__ w2t, const float* __restrict__ b2,
    const float* __restrict__ wsat, const float* __restrict__ bsa,
    float* __restrict__ out1, int useT) {
  __shared__ float h[CIN * HS];
  __shared__ float h1[NH1 * HS];
  __shared__ float pl[256];
  __shared__ float pooled[NH2];
  __shared__ int sidx[NSAMP];
  __shared__ float sc[3];
  const int cid = blockIdx.x;
  const int b = cid >> 11;
  const int s = cid & 2047;
  const int tid = threadIdx.x;
  if (tid < NSAMP) sidx[tid] = bidx[(size_t)cid * NSAMP + tid];
  if (tid < 3) sc[tid] = newxyz[(size_t)cid * 3 + tid];
  __syncthreads();
  {
    const int ss = tid >> 3, q = tid & 7;
    const int j = sidx[ss];
    if (useT) {
      const float4* fr = (const float4*)(fsrc + ((size_t)b * NN + j) * NC + q * 16);
#pragma unroll
      for (int u = 0; u < 4; ++u) {
        float4 v = fr[u];
        int c = 3 + q * 16 + u * 4;
        h[(c + 0) * HS + ss] = v.x;
        h[(c + 1) * HS + ss] = v.y;
        h[(c + 2) * HS + ss] = v.z;
        h[(c + 3) * HS + ss] = v.w;
      }
    } else {
      for (int u = 0; u < 16; ++u) {
        int c = q * 16 + u;
        h[(3 + c) * HS + ss] = fsrc[((size_t)b * NC + c) * NN + j];
      }
    }
    if (q == 0) {
      const float* pr = xyz + ((size_t)b * NN + j) * 3;
      h[0 * HS + ss] = pr[0] - sc[0];
      h[1 * HS + ss] = pr[1] - sc[1];
      h[2 * HS + ss] = pr[2] - sc[2];
    }
  }
  __syncthreads();
  {
    const int o = tid & 63, sg = tid >> 6;
    float acc[8];
    const float bb = b1[o];
#pragma unroll
    for (int i = 0; i < 8; ++i) acc[i] = bb;
    const float4* hb = (const float4*)&h[sg * 8];
    for (int k = 0; k < CIN; ++k) {
      float w = w1t[k * NH1 + o];
      float4 a = hb[k * (HS / 4) + 0];
      float4 c = hb[k * (HS / 4) + 1];
      acc[0] = fmaf(w, a.x, acc[0]); acc[1] = fmaf(w, a.y, acc[1]);
      acc[2] = fmaf(w, a.z, acc[2]); acc[3] = fmaf(w, a.w, acc[3]);
      acc[4] = fmaf(w, c.x, acc[4]); acc[5] = fmaf(w, c.y, acc[5]);
      acc[6] = fmaf(w, c.z, acc[6]); acc[7] = fmaf(w, c.w, acc[7]);
    }
#pragma unroll
    for (int i = 0; i < 8; ++i) h1[o * HS + sg * 8 + i] = fmaxf(acc[i], 0.0f);
  }
  __syncthreads();
  {
    const int o = tid & 127, sg = tid >> 7;
    float acc[16];
    const float bb = b2[o];
#pragma unroll
    for (int i = 0; i < 16; ++i) acc[i] = bb;
    const float4* hb = (const float4*)&h1[sg * 16];
    for (int k = 0; k < NH1; ++k) {
      float w = w2t[k * NH2 + o];
#pragma unroll
      for (int u = 0; u < 4; ++u) {
        float4 a = hb[k * (HS / 4) + u];
        acc[u * 4 + 0] = fmaf(w, a.x, acc[u * 4 + 0]);
        acc[u * 4 + 1] = fmaf(w, a.y, acc[u * 4 + 1]);
        acc[u * 4 + 2] = fmaf(w, a.z, acc[u * 4 + 2]);
        acc[u * 4 + 3] = fmaf(w, a.w, acc[u * 4 + 3]);
      }
    }
    float pm = acc[0];
#pragma unroll
    for (int i = 1; i < 16; ++i) pm = fmaxf(pm, acc[i]);
    pl[sg * 128 + o] = pm;
  }
  __syncthreads();
  if (tid < NH2) pooled[tid] = fmaxf(fmaxf(pl[tid], pl[128 + tid]), 0.0f);
  __syncthreads();
  if (tid < NOUTC) {
    float acc = bsa[tid];
    for (int k = 0; k < NH2; ++k) acc = fmaf(pooled[k], wsat[k * NOUTC + tid], acc);
    out1[((size_t)b * NOUTC + tid) * NPTS + s] = acc;
  }
}

extern "C" void kernel_launch(void* const* d_in, const int* in_sizes, int n_in,
                              void* d_out, int out_size, void* d_ws, size_t ws_size,
                              hipStream_t stream) {
  const float* xyz = (const float*)d_in[0];
  const float* feat = (const float*)d_in[1];
  const float* W1 = (const float*)d_in[2];
  const float* b1 = (const float*)d_in[3];
  const float* W2 = (const float*)d_in[4];
  const float* b2 = (const float*)d_in[5];
  const float* Wsa = (const float*)d_in[6];
  const float* bsa = (const float*)d_in[7];
  float* out = (float*)d_out;
  float* newxyz = out;                       // (B, NPTS, 3)
  float* out1 = out + (size_t)NB * NPTS * 3; // (B, OUT, NPTS)

  const size_t sort_f = (size_t)NB * NN * 4;  // xs, ys, zs, io
  const size_t small_f = (size_t)CIN * NH1 + NH1 * NH2 + NH2 * NOUTC +
                         (size_t)NB * NPTS * NSAMP;
  const size_t featT_f = (size_t)NB * NN * NC;

  float* ws = (float*)d_ws;
  bool useSort = ws_size >= (sort_f + small_f) * 4;
  bool useT = ws_size >= (sort_f + small_f + featT_f) * 4;

  float* xs = ws;
  float* ysr = xs + (size_t)NB * NN;
  float* zsr = ysr + (size_t)NB * NN;
  int* iosr = (int*)(zsr + (size_t)NB * NN);
  float* base2 = useSort ? (ws + sort_f) : ws;
  float* w1t = base2;
  float* w2t = w1t + CIN * NH1;
  float* wsat = w2t + NH1 * NH2;
  int* bidx = (int*)(wsat + NH2 * NOUTC);
  float* featT = (float*)(bidx + (size_t)NB * NPTS * NSAMP);

  tw_kernel<<<64, 256, 0, stream>>>(W1, W2, Wsa, w1t, w2t, wsat);
  if (useT)
    tfeat_kernel<<<dim3(NN / 32, NC / 32, NB), dim3(32, 8), 0, stream>>>(feat, featT);
  if (useSort) {
    sort_kernel<<<NB, 1024, 0, stream>>>(xyz, xs, ysr, zsr, iosr);
    fps_kernel<<<NB, 1024, 0, stream>>>(xyz, xs, ysr, zsr, iosr, newxyz);
  } else {
    fps_nosort_kernel<<<NB, 1024, 0, stream>>>(xyz, newxyz);
  }
  ballq_kernel<<<NB * NPTS / 4, 256, 0, stream>>>(xyz, newxyz, bidx);
  mlp_kernel<<<NB * NPTS, 256, 0, stream>>>(xyz, useT ? featT : feat, newxyz, bidx,
                                            w1t, b1, w2t, b2, wsat, bsa, out1,
                                            (int)useT);
}